// Round 3
// baseline (774.079 us; speedup 1.0000x reference)
//
#include <hip/hip_runtime.h>
#include <math.h>

#define NB 8
#define NT 2048
#define NC 256
#define NV 1024
#define BT (NB*NT)   // 16384 rows

// ---- workspace byte offsets (total need: 77,856 B) ----
#define HIST_OFF 0        // float[1024]            (zeroed)
#define CM_OFF   4096     // double[2] commit,masks (zeroed)
#define EN_OFF   8192     // float[1024] ||e||^2
#define ORD_OFF  12288    // int[16384]
#define KC_OFF   77824    // int[8]
#define WS_REQ   77856

// ---- ||e_c||^2 ----
__global__ void vq_enorm(const float* __restrict__ e, float* __restrict__ en) {
  int c = blockIdx.x, t = threadIdx.x;
  float v = e[(size_t)c * NC + t];
  float s = v * v;
  #pragma unroll
  for (int off = 32; off; off >>= 1) s += __shfl_down(s, off, 64);
  __shared__ float w4[4];
  if ((t & 63) == 0) w4[t >> 6] = s;
  __syncthreads();
  if (t == 0) en[c] = w4[0] + w4[1] + w4[2] + w4[3];
}

// ---- main: distances + argmin + softmax hist, 16 rows/block, wave owns 4 rows x 1024 codes ----
__global__ __launch_bounds__(256, 3) void vq_main(
    const float* __restrict__ z, const float* __restrict__ e,
    const float* __restrict__ mask, const float* __restrict__ en,
    float* __restrict__ hist, float* __restrict__ idxf)
{
  __shared__ __align__(16) float zt[16 * NC];    // 16 KB: block's 16 z rows
  __shared__ __align__(16) float etile[NV * 4];  // 16 KB: e k4-slab, [code][4]
  __shared__ float hlds[NV];                     // 4 KB

  const int tid  = threadIdx.x;
  const int lane = tid & 63;
  const int wv   = tid >> 6;
  const int row0 = blockIdx.x * 16;

  hlds[tid] = 0.f; hlds[tid + 256] = 0.f; hlds[tid + 512] = 0.f; hlds[tid + 768] = 0.f;

  // stage z rows (coalesced float4 copy, linear LDS writes)
  {
    const int r = tid >> 4, cc = tid & 15;
    const float* zr = z + (size_t)(row0 + r) * NC;
    float* dst = zt + r * NC;
    #pragma unroll
    for (int i = 0; i < 4; ++i) {
      float4 v = *(const float4*)(zr + cc * 4 + i * 64);
      *(float4*)(dst + cc * 4 + i * 64) = v;
    }
  }

  float acc[4][16];
  #pragma unroll
  for (int r = 0; r < 4; ++r)
    #pragma unroll
    for (int j = 0; j < 16; ++j) acc[r][j] = 0.f;

  for (int kt = 0; kt < 64; ++kt) {
    const int k0 = kt * 4;
    // load next e k4-slab to registers (no LDS dependence yet)
    float4 ev0 = *(const float4*)(e + (size_t)(0 * 256 + tid) * NC + k0);
    float4 ev1 = *(const float4*)(e + (size_t)(1 * 256 + tid) * NC + k0);
    float4 ev2 = *(const float4*)(e + (size_t)(2 * 256 + tid) * NC + k0);
    float4 ev3 = *(const float4*)(e + (size_t)(3 * 256 + tid) * NC + k0);
    __syncthreads();                     // prev compute done: safe to overwrite etile
    *(float4*)(etile + (0 * 256 + tid) * 4) = ev0;
    *(float4*)(etile + (1 * 256 + tid) * 4) = ev1;
    *(float4*)(etile + (2 * 256 + tid) * 4) = ev2;
    *(float4*)(etile + (3 * 256 + tid) * 4) = ev3;
    __syncthreads();                     // etile (and zt on first iter) visible

    float4 zr0 = *(const float4*)(zt + (wv * 4 + 0) * NC + k0);
    float4 zr1 = *(const float4*)(zt + (wv * 4 + 1) * NC + k0);
    float4 zr2 = *(const float4*)(zt + (wv * 4 + 2) * NC + k0);
    float4 zr3 = *(const float4*)(zt + (wv * 4 + 3) * NC + k0);
    #pragma unroll
    for (int j = 0; j < 16; ++j) {
      float4 ev = *(const float4*)(etile + (j * 64 + lane) * 4);
      acc[0][j] = fmaf(zr0.x, ev.x, acc[0][j]); acc[0][j] = fmaf(zr0.y, ev.y, acc[0][j]);
      acc[0][j] = fmaf(zr0.z, ev.z, acc[0][j]); acc[0][j] = fmaf(zr0.w, ev.w, acc[0][j]);
      acc[1][j] = fmaf(zr1.x, ev.x, acc[1][j]); acc[1][j] = fmaf(zr1.y, ev.y, acc[1][j]);
      acc[1][j] = fmaf(zr1.z, ev.z, acc[1][j]); acc[1][j] = fmaf(zr1.w, ev.w, acc[1][j]);
      acc[2][j] = fmaf(zr2.x, ev.x, acc[2][j]); acc[2][j] = fmaf(zr2.y, ev.y, acc[2][j]);
      acc[2][j] = fmaf(zr2.z, ev.z, acc[2][j]); acc[2][j] = fmaf(zr2.w, ev.w, acc[2][j]);
      acc[3][j] = fmaf(zr3.x, ev.x, acc[3][j]); acc[3][j] = fmaf(zr3.y, ev.y, acc[3][j]);
      acc[3][j] = fmaf(zr3.z, ev.z, acc[3][j]); acc[3][j] = fmaf(zr3.w, ev.w, acc[3][j]);
    }
  }

  // ---- epilogue: s = ||e||^2 - 2*dot; argmin; softmax; hist ----
  float enr[16];
  #pragma unroll
  for (int j = 0; j < 16; ++j) enr[j] = en[j * 64 + lane];
  #pragma unroll
  for (int r = 0; r < 4; ++r)
    #pragma unroll
    for (int j = 0; j < 16; ++j)
      acc[r][j] = fmaf(-2.f, acc[r][j], enr[j]);

  float mrow[4]; int midx[4]; float wgt[4];
  #pragma unroll
  for (int r = 0; r < 4; ++r) {
    float bv = acc[r][0]; int bi = lane;          // j=0 -> code = lane
    #pragma unroll
    for (int j = 1; j < 16; ++j) {
      float v = acc[r][j]; int c = j * 64 + lane;
      if (v < bv || (v == bv && c < bi)) { bv = v; bi = c; }
    }
    #pragma unroll
    for (int off = 32; off; off >>= 1) {          // lexicographic (val,idx) min => first-occurrence argmin
      float ov = __shfl_xor(bv, off, 64);
      int   oi = __shfl_xor(bi, off, 64);
      if (ov < bv || (ov == bv && oi < bi)) { bv = ov; bi = oi; }
    }
    mrow[r] = bv; midx[r] = bi;
  }
  #pragma unroll
  for (int r = 0; r < 4; ++r) {
    float s = 0.f;
    #pragma unroll
    for (int j = 0; j < 16; ++j) {
      float ev = __expf(mrow[r] - acc[r][j]);     // in (0,1], max term = 1
      acc[r][j] = ev; s += ev;
    }
    #pragma unroll
    for (int off = 32; off; off >>= 1) s += __shfl_xor(s, off, 64);
    float mk = mask[row0 + wv * 4 + r];
    wgt[r] = mk / s;
  }
  if (lane == 0) {
    #pragma unroll
    for (int r = 0; r < 4; ++r) {
      int row = row0 + wv * 4 + r;
      idxf[row] = (float)midx[r];
    }
  }
  #pragma unroll
  for (int j = 0; j < 16; ++j) {
    float h = fmaf(wgt[0], acc[0][j], fmaf(wgt[1], acc[1][j],
              fmaf(wgt[2], acc[2][j], wgt[3] * acc[3][j])));
    if (h > 1e-12f) atomicAdd(&hlds[j * 64 + lane], h);   // skip negligible tail mass
  }
  __syncthreads();
  #pragma unroll
  for (int it = 0; it < 4; ++it) {
    float v = hlds[it * 256 + tid];
    if (v > 0.f) atomicAdd(&hist[it * 256 + tid], v);
  }
}

// ---- gather z_q, commitment-loss + mask-sum partials ----
__global__ void vq_gather(const float* __restrict__ z, const float* __restrict__ e,
                          const float* __restrict__ mask, const float* __restrict__ idxf,
                          float* __restrict__ zq, double* __restrict__ cm) {
  int row = blockIdx.x, t = threadIdx.x;
  int id = (int)idxf[row];
  float mv = mask[row];
  float ev = e[(size_t)id * NC + t];
  float zqv = (mv == 0.0f) ? e[t] : ev * mv;     // where(mask==0, pad_e, e[idx]*mask)
  zq[(size_t)row * NC + t] = zqv;
  float zv = z[(size_t)row * NC + t];
  float d = zv - zqv;
  float term = d * d * mv;
  #pragma unroll
  for (int off = 32; off; off >>= 1) term += __shfl_down(term, off, 64);
  __shared__ float w4[4];
  if ((t & 63) == 0) w4[t >> 6] = term;
  __syncthreads();
  if (t == 0) {
    atomicAdd(cm,     (double)(w4[0] + w4[1] + w4[2] + w4[3]));
    atomicAdd(cm + 1, (double)mv);
  }
}

// ---- run-length keep + prefix scan per batch (reads float indices, exact) ----
__global__ void vq_scan(const float* __restrict__ idxf, int* __restrict__ ord, int* __restrict__ Kc) {
  int b = blockIdx.x, t = threadIdx.x;
  const float* ix = idxf + b * NT;
  int flags[8]; int cnt = 0; int base = t * 8;
  #pragma unroll
  for (int i = 0; i < 8; ++i) {
    int g = base + i;
    int k = (g == 0) ? 1 : (ix[g] != ix[g - 1] ? 1 : 0);
    flags[i] = k; cnt += k;
  }
  int lane = t & 63, wv = t >> 6;
  int scan = cnt;
  for (int off = 1; off < 64; off <<= 1) {
    int v = __shfl_up(scan, off, 64);
    if (lane >= off) scan += v;
  }
  __shared__ int wsum[4];
  if (lane == 63) wsum[wv] = scan;
  __syncthreads();
  int woff = 0;
  for (int w = 0; w < wv; ++w) woff += wsum[w];
  int pos = woff + scan - cnt;                    // exclusive prefix for this thread
  #pragma unroll
  for (int i = 0; i < 8; ++i) {
    if (flags[i]) { ord[b * NT + pos] = base + i; ++pos; }
  }
  if (t == 255) Kc[b] = woff + scan;
}

// ---- compact kept rows to front, pad rest with e[0] ----
__global__ void vq_disc(const float* __restrict__ zq, const float* __restrict__ e,
                        const int* __restrict__ ord, const int* __restrict__ Kc,
                        float* __restrict__ disc) {
  int bj = blockIdx.x;
  int b = bj >> 11, j = bj & (NT - 1);
  int t = threadIdx.x;
  int K = Kc[b];
  float v;
  if (j < K) {
    int src = ord[b * NT + j];
    v = zq[((size_t)b * NT + src) * NC + t];
  } else {
    v = e[t];                                     // pad_e
  }
  disc[((size_t)b * NT + j) * NC + t] = v;
}

// ---- losses ----
__global__ void vq_final(const float* __restrict__ hist, const double* __restrict__ cm,
                         float* __restrict__ out) {
  int t = threadIdx.x;
  double l = 0;
  #pragma unroll
  for (int i = 0; i < 4; ++i) l += (double)hist[i * 256 + t];
  #pragma unroll
  for (int off = 32; off; off >>= 1) l += __shfl_down(l, off, 64);
  __shared__ double w4[4];
  __shared__ double tot_s;
  if ((t & 63) == 0) w4[t >> 6] = l;
  __syncthreads();
  if (t == 0) tot_s = w4[0] + w4[1] + w4[2] + w4[3];
  __syncthreads();
  double tot = tot_s + 1e-8;
  double dv = 0;
  #pragma unroll
  for (int i = 0; i < 4; ++i) {
    double p = (double)hist[i * 256 + t] / tot;
    dv += p * log(p * 1024.0 + 1e-8);
  }
  #pragma unroll
  for (int off = 32; off; off >>= 1) dv += __shfl_down(dv, off, 64);
  if ((t & 63) == 0) w4[t >> 6] = dv;
  __syncthreads();
  if (t == 0) {
    out[1] = (float)(w4[0] + w4[1] + w4[2] + w4[3]);
    out[0] = (float)(cm[0] / (cm[1] * 256.0));    // sum / (mask_sum * C)
  }
}

extern "C" void kernel_launch(void* const* d_in, const int* in_sizes, int n_in,
                              void* d_out, int out_size, void* d_ws, size_t ws_size,
                              hipStream_t stream) {
  if (ws_size < (size_t)WS_REQ) return;   // diagnostic guard: absmax-fail (not crash) if scratch too small

  const float* z    = (const float*)d_in[0];
  const float* e    = (const float*)d_in[1];
  const float* mask = (const float*)d_in[2];
  float* out = (float*)d_out;
  char* ws = (char*)d_ws;

  float*  hist  = (float*)(ws + HIST_OFF);
  double* cm    = (double*)(ws + CM_OFF);
  float*  en    = (float*)(ws + EN_OFF);
  int*    ord   = (int*)(ws + ORD_OFF);
  int*    Kc    = (int*)(ws + KC_OFF);

  float* zq   = out + 2;
  float* disc = out + 2 + (size_t)BT * NC;
  float* idxf = out + 2 + (size_t)2 * BT * NC;

  hipMemsetAsync(d_ws, 0, 4112, stream);                       // hist + cm
  vq_enorm <<<NV, NC, 0, stream>>>(e, en);
  vq_main  <<<BT / 16, 256, 0, stream>>>(z, e, mask, en, hist, idxf);
  vq_gather<<<BT, NC, 0, stream>>>(z, e, mask, idxf, zq, cm);
  vq_scan  <<<NB, 256, 0, stream>>>(idxf, ord, Kc);
  vq_disc  <<<BT, NC, 0, stream>>>(zq, e, ord, Kc, disc);
  vq_final <<<1, NC, 0, stream>>>(hist, cm, out);
}

// Round 4
// 389.093 us; speedup vs baseline: 1.9894x; 1.9894x over previous
//
#include <hip/hip_runtime.h>
#include <math.h>

#define NB 8
#define NT 2048
#define NC 256
#define NV 1024
#define BT (NB*NT)   // 16384 rows

// ---- workspace byte offsets (total: 77,856 B — known-good size) ----
#define HIST_OFF  0        // float[1024] (zeroed)
#define EN_OFF    4096     // float[1024] ||e||^2
#define CPART_OFF 8192     // float[1024] per-block commitment partials
#define ORD_OFF   16384    // int[16384]
#define KC_OFF    81920-4096   // = 77824, int[8]
#define WS_REQ    77856

// ---- ||e_c||^2 ----
__global__ void vq_enorm(const float* __restrict__ e, float* __restrict__ en) {
  int c = blockIdx.x, t = threadIdx.x;
  float v = e[(size_t)c * NC + t];
  float s = v * v;
  #pragma unroll
  for (int off = 32; off; off >>= 1) s += __shfl_down(s, off, 64);
  __shared__ float w4[4];
  if ((t & 63) == 0) w4[t >> 6] = s;
  __syncthreads();
  if (t == 0) en[c] = w4[0] + w4[1] + w4[2] + w4[3];
}

// ---- main: distances + argmin + softmax hist, 16 rows/block, wave owns 4 rows x 1024 codes ----
__global__ __launch_bounds__(256, 3) void vq_main(
    const float* __restrict__ z, const float* __restrict__ e,
    const float* __restrict__ mask, const float* __restrict__ en,
    float* __restrict__ hist, float* __restrict__ idxf)
{
  __shared__ __align__(16) float zt[16 * NC];    // 16 KB: block's 16 z rows
  __shared__ __align__(16) float etile[NV * 4];  // 16 KB: e k4-slab, [code][4]
  __shared__ float hlds[NV];                     // 4 KB

  const int tid  = threadIdx.x;
  const int lane = tid & 63;
  const int wv   = tid >> 6;
  const int row0 = blockIdx.x * 16;

  hlds[tid] = 0.f; hlds[tid + 256] = 0.f; hlds[tid + 512] = 0.f; hlds[tid + 768] = 0.f;

  // stage z rows (coalesced float4 copy, linear LDS writes)
  {
    const int r = tid >> 4, cc = tid & 15;
    const float* zr = z + (size_t)(row0 + r) * NC;
    float* dst = zt + r * NC;
    #pragma unroll
    for (int i = 0; i < 4; ++i) {
      float4 v = *(const float4*)(zr + cc * 4 + i * 64);
      *(float4*)(dst + cc * 4 + i * 64) = v;
    }
  }

  float acc[4][16];
  #pragma unroll
  for (int r = 0; r < 4; ++r)
    #pragma unroll
    for (int j = 0; j < 16; ++j) acc[r][j] = 0.f;

  for (int kt = 0; kt < 64; ++kt) {
    const int k0 = kt * 4;
    // load next e k4-slab to registers (no LDS dependence yet)
    float4 ev0 = *(const float4*)(e + (size_t)(0 * 256 + tid) * NC + k0);
    float4 ev1 = *(const float4*)(e + (size_t)(1 * 256 + tid) * NC + k0);
    float4 ev2 = *(const float4*)(e + (size_t)(2 * 256 + tid) * NC + k0);
    float4 ev3 = *(const float4*)(e + (size_t)(3 * 256 + tid) * NC + k0);
    __syncthreads();                     // prev compute done: safe to overwrite etile
    *(float4*)(etile + (0 * 256 + tid) * 4) = ev0;
    *(float4*)(etile + (1 * 256 + tid) * 4) = ev1;
    *(float4*)(etile + (2 * 256 + tid) * 4) = ev2;
    *(float4*)(etile + (3 * 256 + tid) * 4) = ev3;
    __syncthreads();                     // etile (and zt on first iter) visible

    float4 zr0 = *(const float4*)(zt + (wv * 4 + 0) * NC + k0);
    float4 zr1 = *(const float4*)(zt + (wv * 4 + 1) * NC + k0);
    float4 zr2 = *(const float4*)(zt + (wv * 4 + 2) * NC + k0);
    float4 zr3 = *(const float4*)(zt + (wv * 4 + 3) * NC + k0);
    #pragma unroll
    for (int j = 0; j < 16; ++j) {
      float4 ev = *(const float4*)(etile + (j * 64 + lane) * 4);
      acc[0][j] = fmaf(zr0.x, ev.x, acc[0][j]); acc[0][j] = fmaf(zr0.y, ev.y, acc[0][j]);
      acc[0][j] = fmaf(zr0.z, ev.z, acc[0][j]); acc[0][j] = fmaf(zr0.w, ev.w, acc[0][j]);
      acc[1][j] = fmaf(zr1.x, ev.x, acc[1][j]); acc[1][j] = fmaf(zr1.y, ev.y, acc[1][j]);
      acc[1][j] = fmaf(zr1.z, ev.z, acc[1][j]); acc[1][j] = fmaf(zr1.w, ev.w, acc[1][j]);
      acc[2][j] = fmaf(zr2.x, ev.x, acc[2][j]); acc[2][j] = fmaf(zr2.y, ev.y, acc[2][j]);
      acc[2][j] = fmaf(zr2.z, ev.z, acc[2][j]); acc[2][j] = fmaf(zr2.w, ev.w, acc[2][j]);
      acc[3][j] = fmaf(zr3.x, ev.x, acc[3][j]); acc[3][j] = fmaf(zr3.y, ev.y, acc[3][j]);
      acc[3][j] = fmaf(zr3.z, ev.z, acc[3][j]); acc[3][j] = fmaf(zr3.w, ev.w, acc[3][j]);
    }
  }

  // ---- epilogue: s = ||e||^2 - 2*dot; argmin; softmax; hist ----
  float enr[16];
  #pragma unroll
  for (int j = 0; j < 16; ++j) enr[j] = en[j * 64 + lane];
  #pragma unroll
  for (int r = 0; r < 4; ++r)
    #pragma unroll
    for (int j = 0; j < 16; ++j)
      acc[r][j] = fmaf(-2.f, acc[r][j], enr[j]);

  float mrow[4]; int midx[4]; float wgt[4];
  #pragma unroll
  for (int r = 0; r < 4; ++r) {
    float bv = acc[r][0]; int bi = lane;          // j=0 -> code = lane
    #pragma unroll
    for (int j = 1; j < 16; ++j) {
      float v = acc[r][j]; int c = j * 64 + lane;
      if (v < bv || (v == bv && c < bi)) { bv = v; bi = c; }
    }
    #pragma unroll
    for (int off = 32; off; off >>= 1) {          // lexicographic (val,idx) min => first-occurrence argmin
      float ov = __shfl_xor(bv, off, 64);
      int   oi = __shfl_xor(bi, off, 64);
      if (ov < bv || (ov == bv && oi < bi)) { bv = ov; bi = oi; }
    }
    mrow[r] = bv; midx[r] = bi;
  }
  #pragma unroll
  for (int r = 0; r < 4; ++r) {
    float s = 0.f;
    #pragma unroll
    for (int j = 0; j < 16; ++j) {
      float ev = __expf(mrow[r] - acc[r][j]);     // in (0,1], max term = 1
      acc[r][j] = ev; s += ev;
    }
    #pragma unroll
    for (int off = 32; off; off >>= 1) s += __shfl_xor(s, off, 64);
    float mk = mask[row0 + wv * 4 + r];
    wgt[r] = mk / s;
  }
  if (lane == 0) {
    #pragma unroll
    for (int r = 0; r < 4; ++r) {
      int row = row0 + wv * 4 + r;
      idxf[row] = (float)midx[r];
    }
  }
  #pragma unroll
  for (int j = 0; j < 16; ++j) {
    float h = fmaf(wgt[0], acc[0][j], fmaf(wgt[1], acc[1][j],
              fmaf(wgt[2], acc[2][j], wgt[3] * acc[3][j])));
    if (h > 1e-12f) atomicAdd(&hlds[j * 64 + lane], h);   // skip negligible tail mass
  }
  __syncthreads();
  #pragma unroll
  for (int it = 0; it < 4; ++it) {
    float v = hlds[it * 256 + tid];
    if (v > 0.f) atomicAdd(&hist[it * 256 + tid], v);
  }
}

// ---- gather z_q (float4 grid-stride) + per-block commitment partial, NO global atomics ----
__global__ __launch_bounds__(256) void vq_gather(
    const float* __restrict__ z, const float* __restrict__ e,
    const float* __restrict__ mask, const float* __restrict__ idxf,
    float* __restrict__ zq, float* __restrict__ cpart)
{
  const int tid = threadIdx.x, bid = blockIdx.x;
  float cacc = 0.f;
  #pragma unroll
  for (int it = 0; it < 4; ++it) {
    int id  = bid * 1024 + it * 256 + tid;   // float4 index; 1024*1024 total
    int row = id >> 6;                        // 64 float4 per row
    int c4  = (id & 63) << 2;
    int idx = (int)idxf[row];                 // wave-uniform (wave covers one row-slice)
    float mv = mask[row];                     // wave-uniform
    float4 zv = *(const float4*)(z + (size_t)row * NC + c4);
    float4 qv;
    if (mv == 0.0f) {
      qv = *(const float4*)(e + c4);          // pad_e
    } else {
      float4 ev = *(const float4*)(e + (size_t)idx * NC + c4);
      qv = make_float4(ev.x * mv, ev.y * mv, ev.z * mv, ev.w * mv);
    }
    *(float4*)(zq + (size_t)row * NC + c4) = qv;
    float dx = zv.x - qv.x, dy = zv.y - qv.y, dz = zv.z - qv.z, dw = zv.w - qv.w;
    cacc += (dx * dx + dy * dy + dz * dz + dw * dw) * mv;
  }
  #pragma unroll
  for (int off = 32; off; off >>= 1) cacc += __shfl_down(cacc, off, 64);
  __shared__ float w4[4];
  if ((tid & 63) == 0) w4[tid >> 6] = cacc;
  __syncthreads();
  if (tid == 0) cpart[bid] = w4[0] + w4[1] + w4[2] + w4[3];
}

// ---- run-length keep + prefix scan per batch (reads float indices, exact) ----
__global__ void vq_scan(const float* __restrict__ idxf, int* __restrict__ ord, int* __restrict__ Kc) {
  int b = blockIdx.x, t = threadIdx.x;
  const float* ix = idxf + b * NT;
  int flags[8]; int cnt = 0; int base = t * 8;
  #pragma unroll
  for (int i = 0; i < 8; ++i) {
    int g = base + i;
    int k = (g == 0) ? 1 : (ix[g] != ix[g - 1] ? 1 : 0);
    flags[i] = k; cnt += k;
  }
  int lane = t & 63, wv = t >> 6;
  int scan = cnt;
  for (int off = 1; off < 64; off <<= 1) {
    int v = __shfl_up(scan, off, 64);
    if (lane >= off) scan += v;
  }
  __shared__ int wsum[4];
  if (lane == 63) wsum[wv] = scan;
  __syncthreads();
  int woff = 0;
  for (int w = 0; w < wv; ++w) woff += wsum[w];
  int pos = woff + scan - cnt;                    // exclusive prefix for this thread
  #pragma unroll
  for (int i = 0; i < 8; ++i) {
    if (flags[i]) { ord[b * NT + pos] = base + i; ++pos; }
  }
  if (t == 255) Kc[b] = woff + scan;
}

// ---- compact kept rows to front, pad rest with e[0] (float4 grid-stride) ----
__global__ __launch_bounds__(256) void vq_disc(
    const float* __restrict__ zq, const float* __restrict__ e,
    const int* __restrict__ ord, const int* __restrict__ Kc,
    float* __restrict__ disc)
{
  const int tid = threadIdx.x, bid = blockIdx.x;
  #pragma unroll
  for (int it = 0; it < 2; ++it) {
    int id  = bid * 512 + it * 256 + tid;     // float4 index; 2048*512 total
    int row = id >> 6;
    int c4  = (id & 63) << 2;
    int b   = row >> 11;                      // NT = 2048
    int j   = row & (NT - 1);
    int K   = Kc[b];                          // wave-uniform
    float4 v;
    if (j < K) {
      int src = ord[(b << 11) + j];           // wave-uniform
      v = *(const float4*)(zq + ((size_t)(b << 11) + src) * NC + c4);
    } else {
      v = *(const float4*)(e + c4);           // pad_e
    }
    *(float4*)(disc + (size_t)row * NC + c4) = v;
  }
}

// ---- losses: reduce cpart + mask-sum + hist ----
__global__ void vq_final(const float* __restrict__ hist, const float* __restrict__ cpart,
                         const float* __restrict__ mask, float* __restrict__ out) {
  int t = threadIdx.x;
  double csum = 0, msum = 0, hsum = 0;
  #pragma unroll
  for (int i = 0; i < 4; ++i) csum += (double)cpart[i * 256 + t];
  for (int i = t; i < BT; i += 256) msum += (double)mask[i];
  double h[4];
  #pragma unroll
  for (int i = 0; i < 4; ++i) { h[i] = (double)hist[i * 256 + t]; hsum += h[i]; }
  #pragma unroll
  for (int off = 32; off; off >>= 1) {
    csum += __shfl_down(csum, off, 64);
    msum += __shfl_down(msum, off, 64);
    hsum += __shfl_down(hsum, off, 64);
  }
  __shared__ double wc[4], wm[4], wh[4];
  __shared__ double tots[3];
  if ((t & 63) == 0) { int w = t >> 6; wc[w] = csum; wm[w] = msum; wh[w] = hsum; }
  __syncthreads();
  if (t == 0) {
    tots[0] = wc[0] + wc[1] + wc[2] + wc[3];
    tots[1] = wm[0] + wm[1] + wm[2] + wm[3];
    tots[2] = wh[0] + wh[1] + wh[2] + wh[3];
  }
  __syncthreads();
  double tot = tots[2] + 1e-8;
  double dv = 0;
  #pragma unroll
  for (int i = 0; i < 4; ++i) {
    double p = h[i] / tot;
    dv += p * log(p * 1024.0 + 1e-8);
  }
  #pragma unroll
  for (int off = 32; off; off >>= 1) dv += __shfl_down(dv, off, 64);
  if ((t & 63) == 0) wc[t >> 6] = dv;
  __syncthreads();
  if (t == 0) {
    out[1] = (float)(wc[0] + wc[1] + wc[2] + wc[3]);
    out[0] = (float)(tots[0] / (tots[1] * 256.0));   // sum / (mask_sum * C)
  }
}

extern "C" void kernel_launch(void* const* d_in, const int* in_sizes, int n_in,
                              void* d_out, int out_size, void* d_ws, size_t ws_size,
                              hipStream_t stream) {
  if (ws_size < (size_t)WS_REQ) return;   // diagnostic guard

  const float* z    = (const float*)d_in[0];
  const float* e    = (const float*)d_in[1];
  const float* mask = (const float*)d_in[2];
  float* out = (float*)d_out;
  char* ws = (char*)d_ws;

  float* hist  = (float*)(ws + HIST_OFF);
  float* en    = (float*)(ws + EN_OFF);
  float* cpart = (float*)(ws + CPART_OFF);
  int*   ord   = (int*)(ws + ORD_OFF);
  int*   Kc    = (int*)(ws + KC_OFF);

  float* zq   = out + 2;
  float* disc = out + 2 + (size_t)BT * NC;
  float* idxf = out + 2 + (size_t)2 * BT * NC;

  hipMemsetAsync(ws + HIST_OFF, 0, 4096, stream);              // hist only
  vq_enorm <<<NV, NC, 0, stream>>>(e, en);
  vq_main  <<<BT / 16, 256, 0, stream>>>(z, e, mask, en, hist, idxf);
  vq_gather<<<1024, 256, 0, stream>>>(z, e, mask, idxf, zq, cpart);
  vq_scan  <<<NB, 256, 0, stream>>>(idxf, ord, Kc);
  vq_disc  <<<2048, 256, 0, stream>>>(zq, e, ord, Kc, disc);
  vq_final <<<1, NC, 0, stream>>>(hist, cpart, mask, out);
}

// Round 5
// 245.121 us; speedup vs baseline: 3.1579x; 1.5873x over previous
//
#include <hip/hip_runtime.h>
#include <math.h>

#define NB 8
#define NT 2048
#define NC 256
#define NV 1024
#define BT (NB*NT)   // 16384 rows

typedef __attribute__((ext_vector_type(8)))  short bf16x8;
typedef __attribute__((ext_vector_type(8)))  short short8v;
typedef __attribute__((ext_vector_type(16))) float f32x16;

// ---- workspace byte offsets (total: 77,856 B — known-good size) ----
#define HIST_OFF  0        // float[1024] (zeroed)
#define EN_OFF    4096     // float[1024] ||e||^2
#define CPART_OFF 8192     // float[1024] commitment partials
#define ORD_OFF   16384    // int[16384]
#define KC_OFF    77824    // int[8]
#define WS_REQ    77856

// truncated-bf16 limb: returns float value of top-16 bits, outputs the bits
__device__ __forceinline__ float bf_hi(float v, short* bits) {
  unsigned u = __float_as_uint(v);
  *bits = (short)(u >> 16);
  return __uint_as_float(u & 0xffff0000u);
}

// ---- prep: split z into 3 bf16 limbs, k-major per-32-row-block layout ----
// zT[limb] flat bf16 idx = (b*16+s)*512 + h*256 + r*8 + i   (k = s*16+h*8+i)
__global__ __launch_bounds__(256) void vq_prep_z(
    const float* __restrict__ z, short* __restrict__ z1,
    short* __restrict__ z2, short* __restrict__ z3)
{
  __shared__ float zl[32 * NC];
  const int t = threadIdx.x, b = blockIdx.x;
  {
    const int r = t >> 3, cc = (t & 7) * 32;
    const float* zr = z + (size_t)(b * 32 + r) * NC + cc;
    float* dst = zl + r * NC + cc;
    #pragma unroll
    for (int i = 0; i < 8; ++i) *(float4*)(dst + i * 4) = *(const float4*)(zr + i * 4);
  }
  __syncthreads();
  const int s = t >> 4, h = (t >> 3) & 1, rb = (t & 7) * 4;
  const int kb = s * 16 + h * 8;
  #pragma unroll
  for (int rr = 0; rr < 4; ++rr) {
    short8v p1, p2, p3;
    #pragma unroll
    for (int ii = 0; ii < 8; ++ii) {
      float v = zl[(rb + rr) * NC + kb + ii];
      short b1, b2, b3;
      float f1 = bf_hi(v, &b1);
      float r1 = v - f1;
      float f2 = bf_hi(r1, &b2);
      float r2 = r1 - f2;
      bf_hi(r2, &b3);
      p1[ii] = b1; p2[ii] = b2; p3[ii] = b3;
    }
    size_t off = (size_t)(b * 16 + s) * 512 + h * 256 + (rb + rr) * 8;
    *(short8v*)(z1 + off) = p1;
    *(short8v*)(z2 + off) = p2;
    *(short8v*)(z3 + off) = p3;
  }
}

// eT[limb] flat bf16 idx = (s*2+h)*8192 + c*8 + i  (slab s = 32 KB contiguous)
__global__ __launch_bounds__(256) void vq_prep_e(
    const float* __restrict__ e, short* __restrict__ e1,
    short* __restrict__ e2, short* __restrict__ e3)
{
  __shared__ float el[32 * NC];
  const int t = threadIdx.x, cb = blockIdx.x;
  {
    const int r = t >> 3, cc = (t & 7) * 32;
    const float* er = e + (size_t)(cb * 32 + r) * NC + cc;
    float* dst = el + r * NC + cc;
    #pragma unroll
    for (int i = 0; i < 8; ++i) *(float4*)(dst + i * 4) = *(const float4*)(er + i * 4);
  }
  __syncthreads();
  const int s = t >> 4, h = (t >> 3) & 1, rb = (t & 7) * 4;
  const int kb = s * 16 + h * 8;
  #pragma unroll
  for (int rr = 0; rr < 4; ++rr) {
    short8v p1, p2, p3;
    #pragma unroll
    for (int ii = 0; ii < 8; ++ii) {
      float v = el[(rb + rr) * NC + kb + ii];
      short b1, b2, b3;
      float f1 = bf_hi(v, &b1);
      float r1 = v - f1;
      float f2 = bf_hi(r1, &b2);
      float r2 = r1 - f2;
      bf_hi(r2, &b3);
      p1[ii] = b1; p2[ii] = b2; p3[ii] = b3;
    }
    size_t off = (size_t)(s * 2 + h) * 8192 + (size_t)(cb * 32 + rb + rr) * 8;
    *(short8v*)(e1 + off) = p1;
    *(short8v*)(e2 + off) = p2;
    *(short8v*)(e3 + off) = p3;
  }
}

// ---- ||e_c||^2 (f32, from original e) ----
__global__ void vq_enorm(const float* __restrict__ e, float* __restrict__ en) {
  int c = blockIdx.x, t = threadIdx.x;
  float v = e[(size_t)c * NC + t];
  float s = v * v;
  #pragma unroll
  for (int off = 32; off; off >>= 1) s += __shfl_down(s, off, 64);
  __shared__ float w4[4];
  if ((t & 63) == 0) w4[t >> 6] = s;
  __syncthreads();
  if (t == 0) en[c] = w4[0] + w4[1] + w4[2] + w4[3];
}

// ---- main: 6-pass 3-limb bf16 MFMA distances + argmin + softmax hist ----
// block: 512 threads (8 waves), 32 rows; wave owns 128 codes = 4 n-tiles of 32x32
__global__ __launch_bounds__(512, 4) void vq_main_mfma(
    const short* __restrict__ zT1, const short* __restrict__ zT2, const short* __restrict__ zT3,
    const short* __restrict__ eT1, const short* __restrict__ eT2, const short* __restrict__ eT3,
    const float* __restrict__ en, const float* __restrict__ mask,
    float* __restrict__ hist, float* __restrict__ idxf)
{
  __shared__ short Bs[2][16384];     // 2 x 32 KB double-buffered e-limb slab
  __shared__ float pmv[32][8];
  __shared__ int   pmi[32][8];
  __shared__ float psum[32][8];
  __shared__ float mfin[32];
  __shared__ float wrow[32];

  const int tid  = threadIdx.x;
  const int lane = tid & 63, wv = tid >> 6;
  const int l31  = lane & 31, half = lane >> 5;
  const int b = blockIdx.x, row0 = b * 32;

  f32x16 acc[4];
  #pragma unroll
  for (int t = 0; t < 4; ++t)
    #pragma unroll
    for (int r = 0; r < 16; ++r) acc[t][r] = 0.f;

  const short* const zTs[3] = {zT1, zT2, zT3};
  const short* const eTs[3] = {eT1, eT2, eT3};

  #pragma unroll
  for (int L = 0; L < 3; ++L) {
    const short* eT = eTs[L];
    const int nz = 3 - L;                 // z-limbs paired with this e-limb
    { // prologue: stage slab 0 (load before sync, write after)
      const int4* src = (const int4*)eT;
      int4 s0 = src[tid], s1 = src[512 + tid], s2 = src[1024 + tid], s3 = src[1536 + tid];
      __syncthreads();
      int4* dst = (int4*)Bs[0];
      dst[tid] = s0; dst[512 + tid] = s1; dst[1024 + tid] = s2; dst[1536 + tid] = s3;
      __syncthreads();
    }
    for (int s = 0; s < 16; ++s) {
      const int buf = s & 1;
      int4 st0, st1, st2, st3;
      if (s < 15) {                       // T14: issue next-slab loads early
        const int4* src = (const int4*)(eT + (size_t)(s + 1) * 16384);
        st0 = src[tid]; st1 = src[512 + tid]; st2 = src[1024 + tid]; st3 = src[1536 + tid];
      }
      const size_t aoff = (size_t)(b * 16 + s) * 512 + lane * 8;
      bf16x8 a0 = *(const bf16x8*)(zTs[0] + aoff);
      bf16x8 a1 = a0, a2 = a0;
      if (nz > 1) a1 = *(const bf16x8*)(zTs[1] + aoff);
      if (nz > 2) a2 = *(const bf16x8*)(zTs[2] + aoff);
      #pragma unroll
      for (int t = 0; t < 4; ++t) {
        const bf16x8 bfr = *(const bf16x8*)&Bs[buf][(half * 1024 + wv * 128 + t * 32 + l31) * 8];
        acc[t] = __builtin_amdgcn_mfma_f32_32x32x16_bf16(a0, bfr, acc[t], 0, 0, 0);
        if (nz > 1) acc[t] = __builtin_amdgcn_mfma_f32_32x32x16_bf16(a1, bfr, acc[t], 0, 0, 0);
        if (nz > 2) acc[t] = __builtin_amdgcn_mfma_f32_32x32x16_bf16(a2, bfr, acc[t], 0, 0, 0);
      }
      __syncthreads();
      if (s < 15) {
        int4* dst = (int4*)Bs[buf ^ 1];
        dst[tid] = st0; dst[512 + tid] = st1; dst[1024 + tid] = st2; dst[1536 + tid] = st3;
      }
      __syncthreads();
    }
  }

  // ---- epilogue: s = ||e||^2 - 2*dot ----
  // C/D layout (verified): col(code) = l31, row = (r&3) + 8*(r>>2) + 4*half
  float enr[4];
  #pragma unroll
  for (int t = 0; t < 4; ++t) enr[t] = en[wv * 128 + t * 32 + l31];
  #pragma unroll
  for (int t = 0; t < 4; ++t)
    #pragma unroll
    for (int r = 0; r < 16; ++r) acc[t][r] = fmaf(-2.f, acc[t][r], enr[t]);

  // per-row argmin over this wave's 128 codes (butterfly within 32-lane half)
  float bv[16]; int bi[16];
  #pragma unroll
  for (int r = 0; r < 16; ++r) {
    bv[r] = acc[0][r]; bi[r] = wv * 128 + l31;
    #pragma unroll
    for (int t = 1; t < 4; ++t) {
      float vv = acc[t][r]; int cc = wv * 128 + t * 32 + l31;
      if (vv < bv[r]) { bv[r] = vv; bi[r] = cc; }
    }
    #pragma unroll
    for (int off = 1; off <= 16; off <<= 1) {
      float ov = __shfl_xor(bv[r], off, 64);
      int   oi = __shfl_xor(bi[r], off, 64);
      if (ov < bv[r] || (ov == bv[r] && oi < bi[r])) { bv[r] = ov; bi[r] = oi; }
    }
  }
  if (l31 == 0) {
    #pragma unroll
    for (int r = 0; r < 16; ++r) {
      int row = (r & 3) + 8 * (r >> 2) + 4 * half;
      pmv[row][wv] = bv[r]; pmi[row][wv] = bi[r];
    }
  }
  __syncthreads();
  if (tid < 32) {
    float mv = pmv[tid][0]; int mi = pmi[tid][0];
    #pragma unroll
    for (int w = 1; w < 8; ++w) {
      float v = pmv[tid][w]; int i2 = pmi[tid][w];
      if (v < mv || (v == mv && i2 < mi)) { mv = v; mi = i2; }
    }
    mfin[tid] = mv;
    idxf[row0 + tid] = (float)mi;
  }
  __syncthreads();

  // softmax: p = exp(m_row - s), row sums, weights
  #pragma unroll
  for (int r = 0; r < 16; ++r) {
    float m = mfin[(r & 3) + 8 * (r >> 2) + 4 * half];
    float s0 = 0.f;
    #pragma unroll
    for (int t = 0; t < 4; ++t) {
      float p = __expf(m - acc[t][r]);
      acc[t][r] = p; s0 += p;
    }
    #pragma unroll
    for (int off = 1; off <= 16; off <<= 1) s0 += __shfl_xor(s0, off, 64);
    if (l31 == 0) psum[(r & 3) + 8 * (r >> 2) + 4 * half][wv] = s0;
  }
  __syncthreads();
  if (tid < 32) {
    float s0 = 0.f;
    #pragma unroll
    for (int w = 0; w < 8; ++w) s0 += psum[tid][w];
    wrow[tid] = mask[row0 + tid] / s0;
  }
  __syncthreads();

  // hist: per code, sum wgt*p over the block's 32 rows
  #pragma unroll
  for (int t = 0; t < 4; ++t) {
    float h = 0.f;
    #pragma unroll
    for (int r = 0; r < 16; ++r)
      h = fmaf(wrow[(r & 3) + 8 * (r >> 2) + 4 * half], acc[t][r], h);
    h += __shfl_xor(h, 32, 64);
    if (half == 0 && h > 1e-12f) atomicAdd(&hist[wv * 128 + t * 32 + l31], h);
  }
}

// ---- gather z_q (float4 grid-stride) + per-block commitment partial ----
__global__ __launch_bounds__(256) void vq_gather(
    const float* __restrict__ z, const float* __restrict__ e,
    const float* __restrict__ mask, const float* __restrict__ idxf,
    float* __restrict__ zq, float* __restrict__ cpart)
{
  const int tid = threadIdx.x, bid = blockIdx.x;
  float cacc = 0.f;
  #pragma unroll
  for (int it = 0; it < 4; ++it) {
    int id  = bid * 1024 + it * 256 + tid;
    int row = id >> 6;
    int c4  = (id & 63) << 2;
    int idx = (int)idxf[row];
    float mv = mask[row];
    float4 zv = *(const float4*)(z + (size_t)row * NC + c4);
    float4 qv;
    if (mv == 0.0f) {
      qv = *(const float4*)(e + c4);
    } else {
      float4 ev = *(const float4*)(e + (size_t)idx * NC + c4);
      qv = make_float4(ev.x * mv, ev.y * mv, ev.z * mv, ev.w * mv);
    }
    *(float4*)(zq + (size_t)row * NC + c4) = qv;
    float dx = zv.x - qv.x, dy = zv.y - qv.y, dz = zv.z - qv.z, dw = zv.w - qv.w;
    cacc += (dx * dx + dy * dy + dz * dz + dw * dw) * mv;
  }
  #pragma unroll
  for (int off = 32; off; off >>= 1) cacc += __shfl_down(cacc, off, 64);
  __shared__ float w4[4];
  if ((tid & 63) == 0) w4[tid >> 6] = cacc;
  __syncthreads();
  if (tid == 0) cpart[bid] = w4[0] + w4[1] + w4[2] + w4[3];
}

// ---- run-length keep + prefix scan per batch ----
__global__ void vq_scan(const float* __restrict__ idxf, int* __restrict__ ord, int* __restrict__ Kc) {
  int b = blockIdx.x, t = threadIdx.x;
  const float* ix = idxf + b * NT;
  int flags[8]; int cnt = 0; int base = t * 8;
  #pragma unroll
  for (int i = 0; i < 8; ++i) {
    int g = base + i;
    int k = (g == 0) ? 1 : (ix[g] != ix[g - 1] ? 1 : 0);
    flags[i] = k; cnt += k;
  }
  int lane = t & 63, wv = t >> 6;
  int scan = cnt;
  for (int off = 1; off < 64; off <<= 1) {
    int v = __shfl_up(scan, off, 64);
    if (lane >= off) scan += v;
  }
  __shared__ int wsum[4];
  if (lane == 63) wsum[wv] = scan;
  __syncthreads();
  int woff = 0;
  for (int w = 0; w < wv; ++w) woff += wsum[w];
  int pos = woff + scan - cnt;
  #pragma unroll
  for (int i = 0; i < 8; ++i) {
    if (flags[i]) { ord[b * NT + pos] = base + i; ++pos; }
  }
  if (t == 255) Kc[b] = woff + scan;
}

// ---- compact kept rows to front, pad rest with e[0] ----
__global__ __launch_bounds__(256) void vq_disc(
    const float* __restrict__ zq, const float* __restrict__ e,
    const int* __restrict__ ord, const int* __restrict__ Kc,
    float* __restrict__ disc)
{
  const int tid = threadIdx.x, bid = blockIdx.x;
  #pragma unroll
  for (int it = 0; it < 2; ++it) {
    int id  = bid * 512 + it * 256 + tid;
    int row = id >> 6;
    int c4  = (id & 63) << 2;
    int b   = row >> 11;
    int j   = row & (NT - 1);
    int K   = Kc[b];
    float4 v;
    if (j < K) {
      int src = ord[(b << 11) + j];
      v = *(const float4*)(zq + ((size_t)(b << 11) + src) * NC + c4);
    } else {
      v = *(const float4*)(e + c4);
    }
    *(float4*)(disc + (size_t)row * NC + c4) = v;
  }
}

// ---- losses ----
__global__ void vq_final(const float* __restrict__ hist, const float* __restrict__ cpart,
                         const float* __restrict__ mask, float* __restrict__ out) {
  int t = threadIdx.x;
  double csum = 0, msum = 0, hsum = 0;
  #pragma unroll
  for (int i = 0; i < 4; ++i) csum += (double)cpart[i * 256 + t];
  for (int i = t; i < BT; i += 256) msum += (double)mask[i];
  double h[4];
  #pragma unroll
  for (int i = 0; i < 4; ++i) { h[i] = (double)hist[i * 256 + t]; hsum += h[i]; }
  #pragma unroll
  for (int off = 32; off; off >>= 1) {
    csum += __shfl_down(csum, off, 64);
    msum += __shfl_down(msum, off, 64);
    hsum += __shfl_down(hsum, off, 64);
  }
  __shared__ double wc[4], wm[4], wh[4];
  __shared__ double tots[3];
  if ((t & 63) == 0) { int w = t >> 6; wc[w] = csum; wm[w] = msum; wh[w] = hsum; }
  __syncthreads();
  if (t == 0) {
    tots[0] = wc[0] + wc[1] + wc[2] + wc[3];
    tots[1] = wm[0] + wm[1] + wm[2] + wm[3];
    tots[2] = wh[0] + wh[1] + wh[2] + wh[3];
  }
  __syncthreads();
  double tot = tots[2] + 1e-8;
  double dv = 0;
  #pragma unroll
  for (int i = 0; i < 4; ++i) {
    double p = h[i] / tot;
    dv += p * log(p * 1024.0 + 1e-8);
  }
  #pragma unroll
  for (int off = 32; off; off >>= 1) dv += __shfl_down(dv, off, 64);
  if ((t & 63) == 0) wc[t >> 6] = dv;
  __syncthreads();
  if (t == 0) {
    out[1] = (float)(wc[0] + wc[1] + wc[2] + wc[3]);
    out[0] = (float)(tots[0] / (tots[1] * 256.0));
  }
}

extern "C" void kernel_launch(void* const* d_in, const int* in_sizes, int n_in,
                              void* d_out, int out_size, void* d_ws, size_t ws_size,
                              hipStream_t stream) {
  if (ws_size < (size_t)WS_REQ) return;

  const float* z    = (const float*)d_in[0];
  const float* e    = (const float*)d_in[1];
  const float* mask = (const float*)d_in[2];
  float* out = (float*)d_out;
  char* ws = (char*)d_ws;

  float* hist  = (float*)(ws + HIST_OFF);
  float* en    = (float*)(ws + EN_OFF);
  float* cpart = (float*)(ws + CPART_OFF);
  int*   ord   = (int*)(ws + ORD_OFF);
  int*   Kc    = (int*)(ws + KC_OFF);

  float* zq   = out + 2;
  float* disc = out + 2 + (size_t)BT * NC;
  float* idxf = out + 2 + (size_t)2 * BT * NC;

  // limb scratch lives in the zq/disc output regions, overwritten later by
  // vq_gather/vq_disc (stream-ordered after vq_main consumes them)
  short* z1 = (short*)zq;                       // 8.39 MB
  short* z2 = z1 + (size_t)BT * NC;             // 8.39 MB (fills zq region)
  short* z3 = (short*)disc;                     // 8.39 MB
  short* e1 = z3 + (size_t)BT * NC;             // 512 KB
  short* e2 = e1 + (size_t)NV * NC;
  short* e3 = e2 + (size_t)NV * NC;

  hipMemsetAsync(ws + HIST_OFF, 0, 4096, stream);
  vq_prep_z   <<<512, 256, 0, stream>>>(z, z1, z2, z3);
  vq_prep_e   <<<32, 256, 0, stream>>>(e, e1, e2, e3);
  vq_enorm    <<<NV, NC, 0, stream>>>(e, en);
  vq_main_mfma<<<512, 512, 0, stream>>>(z1, z2, z3, e1, e2, e3, en, mask, hist, idxf);
  vq_gather   <<<1024, 256, 0, stream>>>(z, e, mask, idxf, zq, cpart);
  vq_scan     <<<NB, 256, 0, stream>>>(idxf, ord, Kc);
  vq_disc     <<<2048, 256, 0, stream>>>(zq, e, ord, Kc, disc);
  vq_final    <<<1, NC, 0, stream>>>(hist, cpart, mask, out);
}

// Round 6
// 177.612 us; speedup vs baseline: 4.3583x; 1.3801x over previous
//
#include <hip/hip_runtime.h>
#include <math.h>

#define NB 8
#define NT 2048
#define NC 256
#define NV 1024
#define BT (NB*NT)   // 16384 rows

typedef __attribute__((ext_vector_type(8)))  short bf16x8;
typedef __attribute__((ext_vector_type(8)))  short short8v;
typedef __attribute__((ext_vector_type(16))) float f32x16;

// ---- workspace byte offsets (total: 77,856 B — known-good size) ----
#define HIST_OFF  0        // float[1024] (zeroed)
#define EN_OFF    4096     // float[1024] ||e||^2
#define CPART_OFF 8192     // float[1024] commitment partials
#define ORD_OFF   16384    // int[16384]
#define KC_OFF    77824    // int[8]
#define WS_REQ    77856

// truncated-bf16 limb: returns float value of top-16 bits, outputs the bits
__device__ __forceinline__ float bf_hi(float v, short* bits) {
  unsigned u = __float_as_uint(v);
  *bits = (short)(u >> 16);
  return __uint_as_float(u & 0xffff0000u);
}

// ---- prep: split e into 3 bf16 limbs, k-major slab layout ----
// eT[limb] flat bf16 idx = (s*2+h)*8192 + c*8 + i   (k = s*16+h*8+i)
__global__ __launch_bounds__(256) void vq_prep_e(
    const float* __restrict__ e, short* __restrict__ e1,
    short* __restrict__ e2, short* __restrict__ e3)
{
  __shared__ float el[32 * NC];
  const int t = threadIdx.x, cb = blockIdx.x;
  {
    const int r = t >> 3, cc = (t & 7) * 32;
    const float* er = e + (size_t)(cb * 32 + r) * NC + cc;
    float* dst = el + r * NC + cc;
    #pragma unroll
    for (int i = 0; i < 8; ++i) *(float4*)(dst + i * 4) = *(const float4*)(er + i * 4);
  }
  __syncthreads();
  const int s = t >> 4, h = (t >> 3) & 1, rb = (t & 7) * 4;
  const int kb = s * 16 + h * 8;
  #pragma unroll
  for (int rr = 0; rr < 4; ++rr) {
    short8v p1, p2, p3;
    #pragma unroll
    for (int ii = 0; ii < 8; ++ii) {
      float v = el[(rb + rr) * NC + kb + ii];
      short b1, b2, b3;
      float f1 = bf_hi(v, &b1);
      float r1 = v - f1;
      float f2 = bf_hi(r1, &b2);
      float r2 = r1 - f2;
      bf_hi(r2, &b3);
      p1[ii] = b1; p2[ii] = b2; p3[ii] = b3;
    }
    size_t off = (size_t)(s * 2 + h) * 8192 + (size_t)(cb * 32 + rb + rr) * 8;
    *(short8v*)(e1 + off) = p1;
    *(short8v*)(e2 + off) = p2;
    *(short8v*)(e3 + off) = p3;
  }
}

// ---- ||e_c||^2 (f32, from original e) ----
__global__ void vq_enorm(const float* __restrict__ e, float* __restrict__ en) {
  int c = blockIdx.x, t = threadIdx.x;
  float v = e[(size_t)c * NC + t];
  float s = v * v;
  #pragma unroll
  for (int off = 32; off; off >>= 1) s += __shfl_down(s, off, 64);
  __shared__ float w4[4];
  if ((t & 63) == 0) w4[t >> 6] = s;
  __syncthreads();
  if (t == 0) en[c] = w4[0] + w4[1] + w4[2] + w4[3];
}

// ---- main: fused limb-split + 6-product MFMA distances, barrier-free K-loop ----
// block: 512 threads (8 waves), 32 rows; wave owns 128 codes = 4 n-tiles of 32x32
// A/B frag layout (HW-verified by round-5 pass): lane holds row/code l31, k = 8*half + i
__global__ __launch_bounds__(512, 4) void vq_main_fused(
    const float* __restrict__ z,
    const short* __restrict__ eT1, const short* __restrict__ eT2, const short* __restrict__ eT3,
    const float* __restrict__ en, const float* __restrict__ mask,
    float* __restrict__ hist, float* __restrict__ idxf)
{
  __shared__ short zl1[8192], zl2[8192], zl3[8192];  // 48 KB: z limbs, idx = s*512+h*256+r*8+i
  __shared__ float pmv[32][8];
  __shared__ int   pmi[32][8];
  __shared__ float psum[32][8];
  __shared__ float mfin[32];
  __shared__ float wrow[32];

  const int tid  = threadIdx.x;
  const int lane = tid & 63, wv = tid >> 6;
  const int l31  = lane & 31, half = lane >> 5;
  const int b = blockIdx.x, row0 = b * 32;

  // ---- conversion phase: z rows -> 3 limb LDS buffers (one barrier total) ----
  {
    const int s = tid >> 5, r = tid & 31;          // thread owns (slab s, row r), 16 k
    const float* zp = z + (size_t)(row0 + r) * NC + s * 16;
    float v[16];
    #pragma unroll
    for (int i = 0; i < 4; ++i) *(float4*)(v + i * 4) = *(const float4*)(zp + i * 4);
    #pragma unroll
    for (int hh = 0; hh < 2; ++hh) {
      short8v p1, p2, p3;
      #pragma unroll
      for (int ii = 0; ii < 8; ++ii) {
        float x = v[hh * 8 + ii];
        short b1, b2, b3;
        float f1 = bf_hi(x, &b1);
        float r1 = x - f1;
        float f2 = bf_hi(r1, &b2);
        float r2 = r1 - f2;
        bf_hi(r2, &b3);
        p1[ii] = b1; p2[ii] = b2; p3[ii] = b3;
      }
      const int off = s * 512 + hh * 256 + r * 8;
      *(short8v*)&zl1[off] = p1;
      *(short8v*)&zl2[off] = p2;
      *(short8v*)&zl3[off] = p3;
    }
  }
  __syncthreads();

  f32x16 acc[4];
  #pragma unroll
  for (int t = 0; t < 4; ++t)
    #pragma unroll
    for (int r = 0; r < 16; ++r) acc[t][r] = 0.f;

  // ---- barrier-free K-loop: A from LDS, B direct from L2 ----
  for (int s = 0; s < 16; ++s) {
    const int aoff = s * 512 + half * 256 + l31 * 8;
    const bf16x8 a1 = *(const bf16x8*)&zl1[aoff];
    const bf16x8 a2 = *(const bf16x8*)&zl2[aoff];
    const bf16x8 a3 = *(const bf16x8*)&zl3[aoff];
    const size_t bbase = (size_t)(s * 2 + half) * 8192 + (size_t)(wv * 128 + l31) * 8;
    #pragma unroll
    for (int t = 0; t < 4; ++t) {
      const size_t bo = bbase + (size_t)(t * 32) * 8;
      const bf16x8 b1 = *(const bf16x8*)(eT1 + bo);
      const bf16x8 b2 = *(const bf16x8*)(eT2 + bo);
      const bf16x8 b3 = *(const bf16x8*)(eT3 + bo);
      acc[t] = __builtin_amdgcn_mfma_f32_32x32x16_bf16(a1, b1, acc[t], 0, 0, 0);
      acc[t] = __builtin_amdgcn_mfma_f32_32x32x16_bf16(a2, b1, acc[t], 0, 0, 0);
      acc[t] = __builtin_amdgcn_mfma_f32_32x32x16_bf16(a3, b1, acc[t], 0, 0, 0);
      acc[t] = __builtin_amdgcn_mfma_f32_32x32x16_bf16(a1, b2, acc[t], 0, 0, 0);
      acc[t] = __builtin_amdgcn_mfma_f32_32x32x16_bf16(a2, b2, acc[t], 0, 0, 0);
      acc[t] = __builtin_amdgcn_mfma_f32_32x32x16_bf16(a1, b3, acc[t], 0, 0, 0);
    }
  }

  // ---- epilogue: s = ||e||^2 - 2*dot ----
  // C/D layout (verified): col(code) = l31, row = (r&3) + 8*(r>>2) + 4*half
  float enr[4];
  #pragma unroll
  for (int t = 0; t < 4; ++t) enr[t] = en[wv * 128 + t * 32 + l31];
  #pragma unroll
  for (int t = 0; t < 4; ++t)
    #pragma unroll
    for (int r = 0; r < 16; ++r) acc[t][r] = fmaf(-2.f, acc[t][r], enr[t]);

  // per-row argmin over this wave's 128 codes
  float bv[16]; int bi[16];
  #pragma unroll
  for (int r = 0; r < 16; ++r) {
    bv[r] = acc[0][r]; bi[r] = wv * 128 + l31;
    #pragma unroll
    for (int t = 1; t < 4; ++t) {
      float vv = acc[t][r]; int cc = wv * 128 + t * 32 + l31;
      if (vv < bv[r]) { bv[r] = vv; bi[r] = cc; }
    }
    #pragma unroll
    for (int off = 1; off <= 16; off <<= 1) {
      float ov = __shfl_xor(bv[r], off, 64);
      int   oi = __shfl_xor(bi[r], off, 64);
      if (ov < bv[r] || (ov == bv[r] && oi < bi[r])) { bv[r] = ov; bi[r] = oi; }
    }
  }
  if (l31 == 0) {
    #pragma unroll
    for (int r = 0; r < 16; ++r) {
      int row = (r & 3) + 8 * (r >> 2) + 4 * half;
      pmv[row][wv] = bv[r]; pmi[row][wv] = bi[r];
    }
  }
  __syncthreads();
  if (tid < 32) {
    float mv = pmv[tid][0]; int mi = pmi[tid][0];
    #pragma unroll
    for (int w = 1; w < 8; ++w) {
      float v = pmv[tid][w]; int i2 = pmi[tid][w];
      if (v < mv || (v == mv && i2 < mi)) { mv = v; mi = i2; }
    }
    mfin[tid] = mv;
    idxf[row0 + tid] = (float)mi;
  }
  __syncthreads();

  // softmax: p = exp(m_row - s), row sums, weights
  #pragma unroll
  for (int r = 0; r < 16; ++r) {
    float m = mfin[(r & 3) + 8 * (r >> 2) + 4 * half];
    float s0 = 0.f;
    #pragma unroll
    for (int t = 0; t < 4; ++t) {
      float p = __expf(m - acc[t][r]);
      acc[t][r] = p; s0 += p;
    }
    #pragma unroll
    for (int off = 1; off <= 16; off <<= 1) s0 += __shfl_xor(s0, off, 64);
    if (l31 == 0) psum[(r & 3) + 8 * (r >> 2) + 4 * half][wv] = s0;
  }
  __syncthreads();
  if (tid < 32) {
    float s0 = 0.f;
    #pragma unroll
    for (int w = 0; w < 8; ++w) s0 += psum[tid][w];
    wrow[tid] = mask[row0 + tid] / s0;
  }
  __syncthreads();

  // hist: per code, sum wgt*p over the block's 32 rows
  #pragma unroll
  for (int t = 0; t < 4; ++t) {
    float h = 0.f;
    #pragma unroll
    for (int r = 0; r < 16; ++r)
      h = fmaf(wrow[(r & 3) + 8 * (r >> 2) + 4 * half], acc[t][r], h);
    h += __shfl_xor(h, 32, 64);
    if (half == 0 && h > 1e-12f) atomicAdd(&hist[wv * 128 + t * 32 + l31], h);
  }
}

// ---- gather z_q (float4 grid-stride) + per-block commitment partial ----
__global__ __launch_bounds__(256) void vq_gather(
    const float* __restrict__ z, const float* __restrict__ e,
    const float* __restrict__ mask, const float* __restrict__ idxf,
    float* __restrict__ zq, float* __restrict__ cpart)
{
  const int tid = threadIdx.x, bid = blockIdx.x;
  float cacc = 0.f;
  #pragma unroll
  for (int it = 0; it < 4; ++it) {
    int id  = bid * 1024 + it * 256 + tid;
    int row = id >> 6;
    int c4  = (id & 63) << 2;
    int idx = (int)idxf[row];
    float mv = mask[row];
    float4 zv = *(const float4*)(z + (size_t)row * NC + c4);
    float4 qv;
    if (mv == 0.0f) {
      qv = *(const float4*)(e + c4);
    } else {
      float4 ev = *(const float4*)(e + (size_t)idx * NC + c4);
      qv = make_float4(ev.x * mv, ev.y * mv, ev.z * mv, ev.w * mv);
    }
    *(float4*)(zq + (size_t)row * NC + c4) = qv;
    float dx = zv.x - qv.x, dy = zv.y - qv.y, dz = zv.z - qv.z, dw = zv.w - qv.w;
    cacc += (dx * dx + dy * dy + dz * dz + dw * dw) * mv;
  }
  #pragma unroll
  for (int off = 32; off; off >>= 1) cacc += __shfl_down(cacc, off, 64);
  __shared__ float w4[4];
  if ((tid & 63) == 0) w4[tid >> 6] = cacc;
  __syncthreads();
  if (tid == 0) cpart[bid] = w4[0] + w4[1] + w4[2] + w4[3];
}

// ---- run-length keep + prefix scan per batch ----
__global__ void vq_scan(const float* __restrict__ idxf, int* __restrict__ ord, int* __restrict__ Kc) {
  int b = blockIdx.x, t = threadIdx.x;
  const float* ix = idxf + b * NT;
  int flags[8]; int cnt = 0; int base = t * 8;
  #pragma unroll
  for (int i = 0; i < 8; ++i) {
    int g = base + i;
    int k = (g == 0) ? 1 : (ix[g] != ix[g - 1] ? 1 : 0);
    flags[i] = k; cnt += k;
  }
  int lane = t & 63, wv = t >> 6;
  int scan = cnt;
  for (int off = 1; off < 64; off <<= 1) {
    int v = __shfl_up(scan, off, 64);
    if (lane >= off) scan += v;
  }
  __shared__ int wsum[4];
  if (lane == 63) wsum[wv] = scan;
  __syncthreads();
  int woff = 0;
  for (int w = 0; w < wv; ++w) woff += wsum[w];
  int pos = woff + scan - cnt;
  #pragma unroll
  for (int i = 0; i < 8; ++i) {
    if (flags[i]) { ord[b * NT + pos] = base + i; ++pos; }
  }
  if (t == 255) Kc[b] = woff + scan;
}

// ---- compact kept rows to front, pad rest with e[0] ----
__global__ __launch_bounds__(256) void vq_disc(
    const float* __restrict__ zq, const float* __restrict__ e,
    const int* __restrict__ ord, const int* __restrict__ Kc,
    float* __restrict__ disc)
{
  const int tid = threadIdx.x, bid = blockIdx.x;
  #pragma unroll
  for (int it = 0; it < 2; ++it) {
    int id  = bid * 512 + it * 256 + tid;
    int row = id >> 6;
    int c4  = (id & 63) << 2;
    int b   = row >> 11;
    int j   = row & (NT - 1);
    int K   = Kc[b];
    float4 v;
    if (j < K) {
      int src = ord[(b << 11) + j];
      v = *(const float4*)(zq + ((size_t)(b << 11) + src) * NC + c4);
    } else {
      v = *(const float4*)(e + c4);
    }
    *(float4*)(disc + (size_t)row * NC + c4) = v;
  }
}

// ---- losses ----
__global__ void vq_final(const float* __restrict__ hist, const float* __restrict__ cpart,
                         const float* __restrict__ mask, float* __restrict__ out) {
  int t = threadIdx.x;
  double csum = 0, msum = 0, hsum = 0;
  #pragma unroll
  for (int i = 0; i < 4; ++i) csum += (double)cpart[i * 256 + t];
  for (int i = t; i < BT; i += 256) msum += (double)mask[i];
  double h[4];
  #pragma unroll
  for (int i = 0; i < 4; ++i) { h[i] = (double)hist[i * 256 + t]; hsum += h[i]; }
  #pragma unroll
  for (int off = 32; off; off >>= 1) {
    csum += __shfl_down(csum, off, 64);
    msum += __shfl_down(msum, off, 64);
    hsum += __shfl_down(hsum, off, 64);
  }
  __shared__ double wc[4], wm[4], wh[4];
  __shared__ double tots[3];
  if ((t & 63) == 0) { int w = t >> 6; wc[w] = csum; wm[w] = msum; wh[w] = hsum; }
  __syncthreads();
  if (t == 0) {
    tots[0] = wc[0] + wc[1] + wc[2] + wc[3];
    tots[1] = wm[0] + wm[1] + wm[2] + wm[3];
    tots[2] = wh[0] + wh[1] + wh[2] + wh[3];
  }
  __syncthreads();
  double tot = tots[2] + 1e-8;
  double dv = 0;
  #pragma unroll
  for (int i = 0; i < 4; ++i) {
    double p = h[i] / tot;
    dv += p * log(p * 1024.0 + 1e-8);
  }
  #pragma unroll
  for (int off = 32; off; off >>= 1) dv += __shfl_down(dv, off, 64);
  if ((t & 63) == 0) wc[t >> 6] = dv;
  __syncthreads();
  if (t == 0) {
    out[1] = (float)(wc[0] + wc[1] + wc[2] + wc[3]);
    out[0] = (float)(tots[0] / (tots[1] * 256.0));
  }
}

extern "C" void kernel_launch(void* const* d_in, const int* in_sizes, int n_in,
                              void* d_out, int out_size, void* d_ws, size_t ws_size,
                              hipStream_t stream) {
  if (ws_size < (size_t)WS_REQ) return;

  const float* z    = (const float*)d_in[0];
  const float* e    = (const float*)d_in[1];
  const float* mask = (const float*)d_in[2];
  float* out = (float*)d_out;
  char* ws = (char*)d_ws;

  float* hist  = (float*)(ws + HIST_OFF);
  float* en    = (float*)(ws + EN_OFF);
  float* cpart = (float*)(ws + CPART_OFF);
  int*   ord   = (int*)(ws + ORD_OFF);
  int*   Kc    = (int*)(ws + KC_OFF);

  float* zq   = out + 2;
  float* disc = out + 2 + (size_t)BT * NC;
  float* idxf = out + 2 + (size_t)2 * BT * NC;

  // e-limb scratch lives at the start of the disc output region (1.5 MB of
  // 16.8 MB); consumed by vq_main_fused, overwritten later by vq_disc.
  short* e1 = (short*)disc;
  short* e2 = e1 + (size_t)NV * NC;
  short* e3 = e2 + (size_t)NV * NC;

  hipMemsetAsync(ws + HIST_OFF, 0, 4096, stream);
  vq_prep_e    <<<32, 256, 0, stream>>>(e, e1, e2, e3);
  vq_enorm     <<<NV, NC, 0, stream>>>(e, en);
  vq_main_fused<<<512, 512, 0, stream>>>(z, e1, e2, e3, en, mask, hist, idxf);
  vq_gather    <<<1024, 256, 0, stream>>>(z, e, mask, idxf, zq, cpart);
  vq_scan      <<<NB, 256, 0, stream>>>(idxf, ord, Kc);
  vq_disc      <<<2048, 256, 0, stream>>>(zq, e, ord, Kc, disc);
  vq_final     <<<1, NC, 0, stream>>>(hist, cpart, mask, out);
}

// Round 7
// 169.021 us; speedup vs baseline: 4.5798x; 1.0508x over previous
//
#include <hip/hip_runtime.h>
#include <math.h>

#define NB 8
#define NT 2048
#define NC 256
#define NV 1024
#define BT (NB*NT)   // 16384 rows

typedef __attribute__((ext_vector_type(8)))  short bf16x8;
typedef __attribute__((ext_vector_type(8)))  short short8v;
typedef __attribute__((ext_vector_type(16))) float f32x16;

// ---- workspace byte offsets (total: 49,184 B; ws >= 77,856 proven) ----
#define HIST_OFF  0        // float[1024] (zeroed)
#define EN_OFF    4096     // float[1024] ||e||^2
#define CPART_OFF 8192     // float[1024] commitment partials
#define MPART_OFF 12288    // float[1024] mask partials
#define ORD_OFF   16384    // ushort[16384] (positions < 2048)
#define KC_OFF    49152    // int[8]
#define WS_REQ    49184

// truncated-bf16 limb: returns float value of top-16 bits, outputs the bits
__device__ __forceinline__ float bf_hi(float v, short* bits) {
  unsigned u = __float_as_uint(v);
  *bits = (short)(u >> 16);
  return __uint_as_float(u & 0xffff0000u);
}

// ---- prep: split e into 3 bf16 limbs, k-major slab layout ----
// eT[limb] flat bf16 idx = (s*2+h)*8192 + c*8 + i   (k = s*16+h*8+i)
__global__ __launch_bounds__(256) void vq_prep_e(
    const float* __restrict__ e, short* __restrict__ e1,
    short* __restrict__ e2, short* __restrict__ e3)
{
  __shared__ float el[32 * NC];
  const int t = threadIdx.x, cb = blockIdx.x;
  {
    const int r = t >> 3, cc = (t & 7) * 32;
    const float* er = e + (size_t)(cb * 32 + r) * NC + cc;
    float* dst = el + r * NC + cc;
    #pragma unroll
    for (int i = 0; i < 8; ++i) *(float4*)(dst + i * 4) = *(const float4*)(er + i * 4);
  }
  __syncthreads();
  const int s = t >> 4, h = (t >> 3) & 1, rb = (t & 7) * 4;
  const int kb = s * 16 + h * 8;
  #pragma unroll
  for (int rr = 0; rr < 4; ++rr) {
    short8v p1, p2, p3;
    #pragma unroll
    for (int ii = 0; ii < 8; ++ii) {
      float v = el[(rb + rr) * NC + kb + ii];
      short b1, b2, b3;
      float f1 = bf_hi(v, &b1);
      float r1 = v - f1;
      float f2 = bf_hi(r1, &b2);
      float r2 = r1 - f2;
      bf_hi(r2, &b3);
      p1[ii] = b1; p2[ii] = b2; p3[ii] = b3;
    }
    size_t off = (size_t)(s * 2 + h) * 8192 + (size_t)(cb * 32 + rb + rr) * 8;
    *(short8v*)(e1 + off) = p1;
    *(short8v*)(e2 + off) = p2;
    *(short8v*)(e3 + off) = p3;
  }
}

// ---- ||e_c||^2 (f32, from original e) ----
__global__ void vq_enorm(const float* __restrict__ e, float* __restrict__ en) {
  int c = blockIdx.x, t = threadIdx.x;
  float v = e[(size_t)c * NC + t];
  float s = v * v;
  #pragma unroll
  for (int off = 32; off; off >>= 1) s += __shfl_down(s, off, 64);
  __shared__ float w4[4];
  if ((t & 63) == 0) w4[t >> 6] = s;
  __syncthreads();
  if (t == 0) en[c] = w4[0] + w4[1] + w4[2] + w4[3];
}

// ---- main: fused limb-split + 6-product MFMA distances, 64 rows/block ----
// 1024 threads = 16 waves: wave w -> mtile mt=w>>3 (32 rows), code-quad nq=w&7 (128 codes)
__global__ __launch_bounds__(1024, 1) void vq_main_fused(
    const float* __restrict__ z,
    const short* __restrict__ eT1, const short* __restrict__ eT2, const short* __restrict__ eT3,
    const float* __restrict__ en, const float* __restrict__ mask,
    float* __restrict__ hist, float* __restrict__ idxf)
{
  __shared__ short zl1[16384], zl2[16384], zl3[16384];  // 96 KB: 64 rows x 256 k limbs
  __shared__ float pmv[64][8];
  __shared__ int   pmi[64][8];
  __shared__ float psum[64][8];
  __shared__ float mfin[64];
  __shared__ float wrow[64];

  const int tid  = threadIdx.x;
  const int lane = tid & 63, wv = tid >> 6;
  const int l31  = lane & 31, half = lane >> 5;
  const int mt   = wv >> 3, nq = wv & 7;
  const int b = blockIdx.x, row0 = b * 64;

  // ---- conversion: z rows -> 3 limb LDS buffers (one barrier) ----
  {
    const int s = wv, r = lane;                    // wave s, lane = row
    const float* zp = z + (size_t)(row0 + r) * NC + s * 16;
    float v[16];
    #pragma unroll
    for (int i = 0; i < 4; ++i) *(float4*)(v + i * 4) = *(const float4*)(zp + i * 4);
    #pragma unroll
    for (int hh = 0; hh < 2; ++hh) {
      short8v p1, p2, p3;
      #pragma unroll
      for (int ii = 0; ii < 8; ++ii) {
        float x = v[hh * 8 + ii];
        short b1, b2, b3;
        float f1 = bf_hi(x, &b1);
        float r1 = x - f1;
        float f2 = bf_hi(r1, &b2);
        float r2 = r1 - f2;
        bf_hi(r2, &b3);
        p1[ii] = b1; p2[ii] = b2; p3[ii] = b3;
      }
      const int off = (s * 2 + hh) * 512 + r * 8;
      *(short8v*)&zl1[off] = p1;
      *(short8v*)&zl2[off] = p2;
      *(short8v*)&zl3[off] = p3;
    }
  }
  __syncthreads();

  f32x16 acc[4];
  #pragma unroll
  for (int t = 0; t < 4; ++t)
    #pragma unroll
    for (int r = 0; r < 16; ++r) acc[t][r] = 0.f;

  // ---- barrier-free K-loop: A from LDS, B direct from L2 ----
  for (int s = 0; s < 16; ++s) {
    const int aoff = (s * 2 + half) * 512 + (mt * 32 + l31) * 8;
    const bf16x8 a1 = *(const bf16x8*)&zl1[aoff];
    const bf16x8 a2 = *(const bf16x8*)&zl2[aoff];
    const bf16x8 a3 = *(const bf16x8*)&zl3[aoff];
    const size_t bbase = (size_t)(s * 2 + half) * 8192 + (size_t)(nq * 128 + l31) * 8;
    #pragma unroll
    for (int t = 0; t < 4; ++t) {
      const size_t bo = bbase + (size_t)(t * 32) * 8;
      const bf16x8 b1 = *(const bf16x8*)(eT1 + bo);
      const bf16x8 b2 = *(const bf16x8*)(eT2 + bo);
      const bf16x8 b3 = *(const bf16x8*)(eT3 + bo);
      acc[t] = __builtin_amdgcn_mfma_f32_32x32x16_bf16(a1, b1, acc[t], 0, 0, 0);
      acc[t] = __builtin_amdgcn_mfma_f32_32x32x16_bf16(a2, b1, acc[t], 0, 0, 0);
      acc[t] = __builtin_amdgcn_mfma_f32_32x32x16_bf16(a3, b1, acc[t], 0, 0, 0);
      acc[t] = __builtin_amdgcn_mfma_f32_32x32x16_bf16(a1, b2, acc[t], 0, 0, 0);
      acc[t] = __builtin_amdgcn_mfma_f32_32x32x16_bf16(a2, b2, acc[t], 0, 0, 0);
      acc[t] = __builtin_amdgcn_mfma_f32_32x32x16_bf16(a1, b3, acc[t], 0, 0, 0);
    }
  }

  // ---- epilogue: s = ||e||^2 - 2*dot ----
  // C/D layout: col(code) = l31, row = (r&3) + 8*(r>>2) + 4*half
  float enr[4];
  #pragma unroll
  for (int t = 0; t < 4; ++t) enr[t] = en[nq * 128 + t * 32 + l31];
  #pragma unroll
  for (int t = 0; t < 4; ++t)
    #pragma unroll
    for (int r = 0; r < 16; ++r) acc[t][r] = fmaf(-2.f, acc[t][r], enr[t]);

  // per-row argmin over this wave's 128 codes
  float bv[16]; int bi[16];
  #pragma unroll
  for (int r = 0; r < 16; ++r) {
    bv[r] = acc[0][r]; bi[r] = nq * 128 + l31;
    #pragma unroll
    for (int t = 1; t < 4; ++t) {
      float vv = acc[t][r]; int cc = nq * 128 + t * 32 + l31;
      if (vv < bv[r]) { bv[r] = vv; bi[r] = cc; }
    }
    #pragma unroll
    for (int off = 1; off <= 16; off <<= 1) {
      float ov = __shfl_xor(bv[r], off, 64);
      int   oi = __shfl_xor(bi[r], off, 64);
      if (ov < bv[r] || (ov == bv[r] && oi < bi[r])) { bv[r] = ov; bi[r] = oi; }
    }
  }
  if (l31 == 0) {
    #pragma unroll
    for (int r = 0; r < 16; ++r) {
      int rowb = mt * 32 + (r & 3) + 8 * (r >> 2) + 4 * half;
      pmv[rowb][nq] = bv[r]; pmi[rowb][nq] = bi[r];
    }
  }
  __syncthreads();
  if (tid < 64) {
    float mv = pmv[tid][0]; int mi = pmi[tid][0];
    #pragma unroll
    for (int w = 1; w < 8; ++w) {
      float v = pmv[tid][w]; int i2 = pmi[tid][w];
      if (v < mv || (v == mv && i2 < mi)) { mv = v; mi = i2; }
    }
    mfin[tid] = mv;
    idxf[row0 + tid] = (float)mi;
  }
  __syncthreads();

  // softmax: p = exp(m_row - s), row sums, weights
  #pragma unroll
  for (int r = 0; r < 16; ++r) {
    const int rowb = mt * 32 + (r & 3) + 8 * (r >> 2) + 4 * half;
    float m = mfin[rowb];
    float s0 = 0.f;
    #pragma unroll
    for (int t = 0; t < 4; ++t) {
      float p = __expf(m - acc[t][r]);
      acc[t][r] = p; s0 += p;
    }
    #pragma unroll
    for (int off = 1; off <= 16; off <<= 1) s0 += __shfl_xor(s0, off, 64);
    if (l31 == 0) psum[rowb][nq] = s0;
  }
  __syncthreads();
  if (tid < 64) {
    float s0 = 0.f;
    #pragma unroll
    for (int w = 0; w < 8; ++w) s0 += psum[tid][w];
    wrow[tid] = mask[row0 + tid] / s0;
  }
  __syncthreads();

  // hist: per code, sum wgt*p over this wave's 32 rows; atomic-combine
  #pragma unroll
  for (int t = 0; t < 4; ++t) {
    float h = 0.f;
    #pragma unroll
    for (int r = 0; r < 16; ++r)
      h = fmaf(wrow[mt * 32 + (r & 3) + 8 * (r >> 2) + 4 * half], acc[t][r], h);
    h += __shfl_xor(h, 32, 64);
    if (half == 0 && h > 1e-12f) atomicAdd(&hist[nq * 128 + t * 32 + l31], h);
  }
}

// ---- gather z_q (float4 grid-stride) + commitment & mask partials ----
__global__ __launch_bounds__(256) void vq_gather(
    const float* __restrict__ z, const float* __restrict__ e,
    const float* __restrict__ mask, const float* __restrict__ idxf,
    float* __restrict__ zq, float* __restrict__ cpart, float* __restrict__ mpart)
{
  const int tid = threadIdx.x, bid = blockIdx.x;
  float cacc = 0.f, macc = 0.f;
  #pragma unroll
  for (int it = 0; it < 4; ++it) {
    int id  = bid * 1024 + it * 256 + tid;
    int row = id >> 6;
    int c4  = (id & 63) << 2;
    int idx = (int)idxf[row];
    float mv = mask[row];
    float4 zv = *(const float4*)(z + (size_t)row * NC + c4);
    float4 qv;
    if (mv == 0.0f) {
      qv = *(const float4*)(e + c4);
    } else {
      float4 ev = *(const float4*)(e + (size_t)idx * NC + c4);
      qv = make_float4(ev.x * mv, ev.y * mv, ev.z * mv, ev.w * mv);
    }
    *(float4*)(zq + (size_t)row * NC + c4) = qv;
    float dx = zv.x - qv.x, dy = zv.y - qv.y, dz = zv.z - qv.z, dw = zv.w - qv.w;
    cacc += (dx * dx + dy * dy + dz * dz + dw * dw) * mv;
    macc += mv;                                   // each row counted 64x
  }
  #pragma unroll
  for (int off = 32; off; off >>= 1) {
    cacc += __shfl_down(cacc, off, 64);
    macc += __shfl_down(macc, off, 64);
  }
  __shared__ float w4[4], m4[4];
  if ((tid & 63) == 0) { w4[tid >> 6] = cacc; m4[tid >> 6] = macc; }
  __syncthreads();
  if (tid == 0) {
    cpart[bid] = w4[0] + w4[1] + w4[2] + w4[3];
    mpart[bid] = (m4[0] + m4[1] + m4[2] + m4[3]) * (1.0f / 64.0f);
  }
}

// ---- run-length keep + prefix scan per batch ----
__global__ void vq_scan(const float* __restrict__ idxf, unsigned short* __restrict__ ord,
                        int* __restrict__ Kc) {
  int b = blockIdx.x, t = threadIdx.x;
  const float* ix = idxf + b * NT;
  int flags[8]; int cnt = 0; int base = t * 8;
  #pragma unroll
  for (int i = 0; i < 8; ++i) {
    int g = base + i;
    int k = (g == 0) ? 1 : (ix[g] != ix[g - 1] ? 1 : 0);
    flags[i] = k; cnt += k;
  }
  int lane = t & 63, wv = t >> 6;
  int scan = cnt;
  for (int off = 1; off < 64; off <<= 1) {
    int v = __shfl_up(scan, off, 64);
    if (lane >= off) scan += v;
  }
  __shared__ int wsum[4];
  if (lane == 63) wsum[wv] = scan;
  __syncthreads();
  int woff = 0;
  for (int w = 0; w < wv; ++w) woff += wsum[w];
  int pos = woff + scan - cnt;
  #pragma unroll
  for (int i = 0; i < 8; ++i) {
    if (flags[i]) { ord[b * NT + pos] = (unsigned short)(base + i); ++pos; }
  }
  if (t == 255) Kc[b] = woff + scan;
}

// ---- compact kept rows to front, pad rest with e[0] ----
__global__ __launch_bounds__(256) void vq_disc(
    const float* __restrict__ zq, const float* __restrict__ e,
    const unsigned short* __restrict__ ord, const int* __restrict__ Kc,
    float* __restrict__ disc)
{
  const int tid = threadIdx.x, bid = blockIdx.x;
  #pragma unroll
  for (int it = 0; it < 2; ++it) {
    int id  = bid * 512 + it * 256 + tid;
    int row = id >> 6;
    int c4  = (id & 63) << 2;
    int b   = row >> 11;
    int j   = row & (NT - 1);
    int K   = Kc[b];
    float4 v;
    if (j < K) {
      int src = ord[(b << 11) + j];
      v = *(const float4*)(zq + ((size_t)(b << 11) + src) * NC + c4);
    } else {
      v = *(const float4*)(e + c4);
    }
    *(float4*)(disc + (size_t)row * NC + c4) = v;
  }
}

// ---- losses ----
__global__ void vq_final(const float* __restrict__ hist, const float* __restrict__ cpart,
                         const float* __restrict__ mpart, float* __restrict__ out) {
  int t = threadIdx.x;
  double csum = 0, msum = 0, hsum = 0;
  #pragma unroll
  for (int i = 0; i < 4; ++i) {
    csum += (double)cpart[i * 256 + t];
    msum += (double)mpart[i * 256 + t];
  }
  double h[4];
  #pragma unroll
  for (int i = 0; i < 4; ++i) { h[i] = (double)hist[i * 256 + t]; hsum += h[i]; }
  #pragma unroll
  for (int off = 32; off; off >>= 1) {
    csum += __shfl_down(csum, off, 64);
    msum += __shfl_down(msum, off, 64);
    hsum += __shfl_down(hsum, off, 64);
  }
  __shared__ double wc[4], wm[4], wh[4];
  __shared__ double tots[3];
  if ((t & 63) == 0) { int w = t >> 6; wc[w] = csum; wm[w] = msum; wh[w] = hsum; }
  __syncthreads();
  if (t == 0) {
    tots[0] = wc[0] + wc[1] + wc[2] + wc[3];
    tots[1] = wm[0] + wm[1] + wm[2] + wm[3];
    tots[2] = wh[0] + wh[1] + wh[2] + wh[3];
  }
  __syncthreads();
  double tot = tots[2] + 1e-8;
  double dv = 0;
  #pragma unroll
  for (int i = 0; i < 4; ++i) {
    double p = h[i] / tot;
    dv += p * log(p * 1024.0 + 1e-8);
  }
  #pragma unroll
  for (int off = 32; off; off >>= 1) dv += __shfl_down(dv, off, 64);
  if ((t & 63) == 0) wc[t >> 6] = dv;
  __syncthreads();
  if (t == 0) {
    out[1] = (float)(wc[0] + wc[1] + wc[2] + wc[3]);
    out[0] = (float)(tots[0] / (tots[1] * 256.0));
  }
}

extern "C" void kernel_launch(void* const* d_in, const int* in_sizes, int n_in,
                              void* d_out, int out_size, void* d_ws, size_t ws_size,
                              hipStream_t stream) {
  if (ws_size < (size_t)WS_REQ) return;

  const float* z    = (const float*)d_in[0];
  const float* e    = (const float*)d_in[1];
  const float* mask = (const float*)d_in[2];
  float* out = (float*)d_out;
  char* ws = (char*)d_ws;

  float*          hist  = (float*)(ws + HIST_OFF);
  float*          en    = (float*)(ws + EN_OFF);
  float*          cpart = (float*)(ws + CPART_OFF);
  float*          mpart = (float*)(ws + MPART_OFF);
  unsigned short* ord   = (unsigned short*)(ws + ORD_OFF);
  int*            Kc    = (int*)(ws + KC_OFF);

  float* zq   = out + 2;
  float* disc = out + 2 + (size_t)BT * NC;
  float* idxf = out + 2 + (size_t)2 * BT * NC;

  // e-limb scratch lives at the start of the disc output region (1.5 MB of
  // 16.8 MB); consumed by vq_main_fused, overwritten later by vq_disc.
  short* e1 = (short*)disc;
  short* e2 = e1 + (size_t)NV * NC;
  short* e3 = e2 + (size_t)NV * NC;

  hipMemsetAsync(ws + HIST_OFF, 0, 4096, stream);
  vq_prep_e    <<<32, 256, 0, stream>>>(e, e1, e2, e3);
  vq_enorm     <<<NV, NC, 0, stream>>>(e, en);
  vq_main_fused<<<256, 1024, 0, stream>>>(z, e1, e2, e3, en, mask, hist, idxf);
  vq_gather    <<<1024, 256, 0, stream>>>(z, e, mask, idxf, zq, cpart, mpart);
  vq_scan      <<<NB, 256, 0, stream>>>(idxf, ord, Kc);
  vq_disc      <<<2048, 256, 0, stream>>>(zq, e, ord, Kc, disc);
  vq_final     <<<1, NC, 0, stream>>>(hist, cpart, mpart, out);
}

// Round 8
// 167.871 us; speedup vs baseline: 4.6112x; 1.0069x over previous
//
#include <hip/hip_runtime.h>
#include <math.h>

#define NB 8
#define NT 2048
#define NC 256
#define NV 1024
#define BT (NB*NT)   // 16384 rows

typedef __attribute__((ext_vector_type(8)))  short bf16x8;
typedef __attribute__((ext_vector_type(8)))  short short8v;
typedef __attribute__((ext_vector_type(16))) float f32x16;

// ---- workspace byte offsets (total: 49,184 B; ws >= 77,856 proven) ----
#define HIST_OFF  0        // float[1024] (zeroed)
#define EN_OFF    4096     // float[1024] ||e||^2
#define CPART_OFF 8192     // float[1024] commitment partials
#define MPART_OFF 12288    // float[1024] mask partials
#define ORD_OFF   16384    // ushort[16384] (positions < 2048)
#define KC_OFF    49152    // int[8]
#define WS_REQ    49184

// truncated-bf16 limb: returns float value of top-16 bits, outputs the bits
__device__ __forceinline__ float bf_hi(float v, short* bits) {
  unsigned u = __float_as_uint(v);
  *bits = (short)(u >> 16);
  return __uint_as_float(u & 0xffff0000u);
}

// ---- prep: split e into 3 bf16 limbs (k-major slabs) + fused ||e||^2 ----
// eT[limb] flat bf16 idx = (s*2+h)*8192 + c*8 + i   (k = s*16+h*8+i)
__global__ __launch_bounds__(256) void vq_prep_e(
    const float* __restrict__ e, short* __restrict__ e1,
    short* __restrict__ e2, short* __restrict__ e3, float* __restrict__ en)
{
  __shared__ float el[32 * NC];
  const int t = threadIdx.x, cb = blockIdx.x;
  {
    const int r = t >> 3, cc = (t & 7) * 32;
    const float* er = e + (size_t)(cb * 32 + r) * NC + cc;
    float* dst = el + r * NC + cc;
    float ss = 0.f;
    #pragma unroll
    for (int i = 0; i < 8; ++i) {
      float4 v = *(const float4*)(er + i * 4);
      *(float4*)(dst + i * 4) = v;
      ss += v.x * v.x + v.y * v.y + v.z * v.z + v.w * v.w;
    }
    #pragma unroll
    for (int off = 1; off < 8; off <<= 1) ss += __shfl_xor(ss, off, 64);
    if ((t & 7) == 0) en[cb * 32 + r] = ss;       // 8 threads/row share a wave
  }
  __syncthreads();
  const int s = t >> 4, h = (t >> 3) & 1, rb = (t & 7) * 4;
  const int kb = s * 16 + h * 8;
  #pragma unroll
  for (int rr = 0; rr < 4; ++rr) {
    short8v p1, p2, p3;
    #pragma unroll
    for (int ii = 0; ii < 8; ++ii) {
      float v = el[(rb + rr) * NC + kb + ii];
      short b1, b2, b3;
      float f1 = bf_hi(v, &b1);
      float r1 = v - f1;
      float f2 = bf_hi(r1, &b2);
      float r2 = r1 - f2;
      bf_hi(r2, &b3);
      p1[ii] = b1; p2[ii] = b2; p3[ii] = b3;
    }
    size_t off = (size_t)(s * 2 + h) * 8192 + (size_t)(cb * 32 + rb + rr) * 8;
    *(short8v*)(e1 + off) = p1;
    *(short8v*)(e2 + off) = p2;
    *(short8v*)(e3 + off) = p3;
  }
}

// ---- main: fused limb-split + 6-product MFMA distances, 64 rows/block ----
// 1024 threads = 16 waves: wave w -> mtile mt=w>>3 (32 rows), code-quad nq=w&7 (128 codes)
// K-loop: staggered slab order (L2-channel spread) + full unroll (B prefetch)
__global__ __launch_bounds__(1024, 1) void vq_main_fused(
    const float* __restrict__ z,
    const short* __restrict__ eT1, const short* __restrict__ eT2, const short* __restrict__ eT3,
    const float* __restrict__ en, const float* __restrict__ mask,
    float* __restrict__ hist, float* __restrict__ idxf)
{
  __shared__ short zl1[16384], zl2[16384], zl3[16384];  // 96 KB: 64 rows x 256 k limbs
  __shared__ float pmv[64][8];
  __shared__ int   pmi[64][8];
  __shared__ float psum[64][8];
  __shared__ float mfin[64];
  __shared__ float wrow[64];

  const int tid  = threadIdx.x;
  const int lane = tid & 63, wv = tid >> 6;
  const int l31  = lane & 31, half = lane >> 5;
  const int mt   = wv >> 3, nq = wv & 7;
  const int b = blockIdx.x, row0 = b * 64;

  // ---- conversion: z rows -> 3 limb LDS buffers (one barrier) ----
  {
    const int s = wv, r = lane;                    // wave s, lane = row
    const float* zp = z + (size_t)(row0 + r) * NC + s * 16;
    float v[16];
    #pragma unroll
    for (int i = 0; i < 4; ++i) *(float4*)(v + i * 4) = *(const float4*)(zp + i * 4);
    #pragma unroll
    for (int hh = 0; hh < 2; ++hh) {
      short8v p1, p2, p3;
      #pragma unroll
      for (int ii = 0; ii < 8; ++ii) {
        float x = v[hh * 8 + ii];
        short b1, b2, b3;
        float f1 = bf_hi(x, &b1);
        float r1 = x - f1;
        float f2 = bf_hi(r1, &b2);
        float r2 = r1 - f2;
        bf_hi(r2, &b3);
        p1[ii] = b1; p2[ii] = b2; p3[ii] = b3;
      }
      const int off = (s * 2 + hh) * 512 + r * 8;
      *(short8v*)&zl1[off] = p1;
      *(short8v*)&zl2[off] = p2;
      *(short8v*)&zl3[off] = p3;
    }
  }
  __syncthreads();

  f32x16 acc[4];
  #pragma unroll
  for (int t = 0; t < 4; ++t)
    #pragma unroll
    for (int r = 0; r < 16; ++r) acc[t][r] = 0.f;

  // ---- barrier-free K-loop: A from LDS, B from L2; staggered + unrolled ----
  const int sb = b & 15;                 // per-block slab rotation
  #pragma unroll
  for (int ss = 0; ss < 16; ++ss) {
    const int s = (ss + sb) & 15;
    const int aoff = (s * 2 + half) * 512 + (mt * 32 + l31) * 8;
    const bf16x8 a1 = *(const bf16x8*)&zl1[aoff];
    const bf16x8 a2 = *(const bf16x8*)&zl2[aoff];
    const bf16x8 a3 = *(const bf16x8*)&zl3[aoff];
    const size_t bbase = (size_t)(s * 2 + half) * 8192 + (size_t)(nq * 128 + l31) * 8;
    #pragma unroll
    for (int t = 0; t < 4; ++t) {
      const size_t bo = bbase + (size_t)(t * 32) * 8;
      const bf16x8 b1 = *(const bf16x8*)(eT1 + bo);
      const bf16x8 b2 = *(const bf16x8*)(eT2 + bo);
      const bf16x8 b3 = *(const bf16x8*)(eT3 + bo);
      acc[t] = __builtin_amdgcn_mfma_f32_32x32x16_bf16(a1, b1, acc[t], 0, 0, 0);
      acc[t] = __builtin_amdgcn_mfma_f32_32x32x16_bf16(a2, b1, acc[t], 0, 0, 0);
      acc[t] = __builtin_amdgcn_mfma_f32_32x32x16_bf16(a3, b1, acc[t], 0, 0, 0);
      acc[t] = __builtin_amdgcn_mfma_f32_32x32x16_bf16(a1, b2, acc[t], 0, 0, 0);
      acc[t] = __builtin_amdgcn_mfma_f32_32x32x16_bf16(a2, b2, acc[t], 0, 0, 0);
      acc[t] = __builtin_amdgcn_mfma_f32_32x32x16_bf16(a1, b3, acc[t], 0, 0, 0);
    }
  }

  // ---- epilogue: s = ||e||^2 - 2*dot ----
  // C/D layout: col(code) = l31, row = (r&3) + 8*(r>>2) + 4*half
  float enr[4];
  #pragma unroll
  for (int t = 0; t < 4; ++t) enr[t] = en[nq * 128 + t * 32 + l31];
  #pragma unroll
  for (int t = 0; t < 4; ++t)
    #pragma unroll
    for (int r = 0; r < 16; ++r) acc[t][r] = fmaf(-2.f, acc[t][r], enr[t]);

  // per-row argmin over this wave's 128 codes
  float bv[16]; int bi[16];
  #pragma unroll
  for (int r = 0; r < 16; ++r) {
    bv[r] = acc[0][r]; bi[r] = nq * 128 + l31;
    #pragma unroll
    for (int t = 1; t < 4; ++t) {
      float vv = acc[t][r]; int cc = nq * 128 + t * 32 + l31;
      if (vv < bv[r]) { bv[r] = vv; bi[r] = cc; }
    }
    #pragma unroll
    for (int off = 1; off <= 16; off <<= 1) {
      float ov = __shfl_xor(bv[r], off, 64);
      int   oi = __shfl_xor(bi[r], off, 64);
      if (ov < bv[r] || (ov == bv[r] && oi < bi[r])) { bv[r] = ov; bi[r] = oi; }
    }
  }
  if (l31 == 0) {
    #pragma unroll
    for (int r = 0; r < 16; ++r) {
      int rowb = mt * 32 + (r & 3) + 8 * (r >> 2) + 4 * half;
      pmv[rowb][nq] = bv[r]; pmi[rowb][nq] = bi[r];
    }
  }
  __syncthreads();
  if (tid < 64) {
    float mv = pmv[tid][0]; int mi = pmi[tid][0];
    #pragma unroll
    for (int w = 1; w < 8; ++w) {
      float v = pmv[tid][w]; int i2 = pmi[tid][w];
      if (v < mv || (v == mv && i2 < mi)) { mv = v; mi = i2; }
    }
    mfin[tid] = mv;
    idxf[row0 + tid] = (float)mi;
  }
  __syncthreads();

  // softmax: p = exp(m_row - s), row sums, weights
  #pragma unroll
  for (int r = 0; r < 16; ++r) {
    const int rowb = mt * 32 + (r & 3) + 8 * (r >> 2) + 4 * half;
    float m = mfin[rowb];
    float s0 = 0.f;
    #pragma unroll
    for (int t = 0; t < 4; ++t) {
      float p = __expf(m - acc[t][r]);
      acc[t][r] = p; s0 += p;
    }
    #pragma unroll
    for (int off = 1; off <= 16; off <<= 1) s0 += __shfl_xor(s0, off, 64);
    if (l31 == 0) psum[rowb][nq] = s0;
  }
  __syncthreads();
  if (tid < 64) {
    float s0 = 0.f;
    #pragma unroll
    for (int w = 0; w < 8; ++w) s0 += psum[tid][w];
    wrow[tid] = mask[row0 + tid] / s0;
  }
  __syncthreads();

  // hist: per code, sum wgt*p over this wave's 32 rows; atomic-combine
  #pragma unroll
  for (int t = 0; t < 4; ++t) {
    float h = 0.f;
    #pragma unroll
    for (int r = 0; r < 16; ++r)
      h = fmaf(wrow[mt * 32 + (r & 3) + 8 * (r >> 2) + 4 * half], acc[t][r], h);
    h += __shfl_xor(h, 32, 64);
    if (half == 0 && h > 1e-12f) atomicAdd(&hist[nq * 128 + t * 32 + l31], h);
  }
}

// ---- gather z_q (float4 grid-stride) + commitment & mask partials ----
__global__ __launch_bounds__(256) void vq_gather(
    const float* __restrict__ z, const float* __restrict__ e,
    const float* __restrict__ mask, const float* __restrict__ idxf,
    float* __restrict__ zq, float* __restrict__ cpart, float* __restrict__ mpart)
{
  const int tid = threadIdx.x, bid = blockIdx.x;
  float cacc = 0.f, macc = 0.f;
  #pragma unroll
  for (int it = 0; it < 4; ++it) {
    int id  = bid * 1024 + it * 256 + tid;
    int row = id >> 6;
    int c4  = (id & 63) << 2;
    int idx = (int)idxf[row];
    float mv = mask[row];
    float4 zv = *(const float4*)(z + (size_t)row * NC + c4);
    float4 qv;
    if (mv == 0.0f) {
      qv = *(const float4*)(e + c4);
    } else {
      float4 ev = *(const float4*)(e + (size_t)idx * NC + c4);
      qv = make_float4(ev.x * mv, ev.y * mv, ev.z * mv, ev.w * mv);
    }
    *(float4*)(zq + (size_t)row * NC + c4) = qv;
    float dx = zv.x - qv.x, dy = zv.y - qv.y, dz = zv.z - qv.z, dw = zv.w - qv.w;
    cacc += (dx * dx + dy * dy + dz * dz + dw * dw) * mv;
    macc += mv;                                   // each row counted 64x
  }
  #pragma unroll
  for (int off = 32; off; off >>= 1) {
    cacc += __shfl_down(cacc, off, 64);
    macc += __shfl_down(macc, off, 64);
  }
  __shared__ float w4[4], m4[4];
  if ((tid & 63) == 0) { w4[tid >> 6] = cacc; m4[tid >> 6] = macc; }
  __syncthreads();
  if (tid == 0) {
    cpart[bid] = w4[0] + w4[1] + w4[2] + w4[3];
    mpart[bid] = (m4[0] + m4[1] + m4[2] + m4[3]) * (1.0f / 64.0f);
  }
}

// ---- run-length keep + prefix scan per batch ----
__global__ void vq_scan(const float* __restrict__ idxf, unsigned short* __restrict__ ord,
                        int* __restrict__ Kc) {
  int b = blockIdx.x, t = threadIdx.x;
  const float* ix = idxf + b * NT;
  int flags[8]; int cnt = 0; int base = t * 8;
  #pragma unroll
  for (int i = 0; i < 8; ++i) {
    int g = base + i;
    int k = (g == 0) ? 1 : (ix[g] != ix[g - 1] ? 1 : 0);
    flags[i] = k; cnt += k;
  }
  int lane = t & 63, wv = t >> 6;
  int scan = cnt;
  for (int off = 1; off < 64; off <<= 1) {
    int v = __shfl_up(scan, off, 64);
    if (lane >= off) scan += v;
  }
  __shared__ int wsum[4];
  if (lane == 63) wsum[wv] = scan;
  __syncthreads();
  int woff = 0;
  for (int w = 0; w < wv; ++w) woff += wsum[w];
  int pos = woff + scan - cnt;
  #pragma unroll
  for (int i = 0; i < 8; ++i) {
    if (flags[i]) { ord[b * NT + pos] = (unsigned short)(base + i); ++pos; }
  }
  if (t == 255) Kc[b] = woff + scan;
}

// ---- compact kept rows to front, pad rest with e[0] ----
__global__ __launch_bounds__(256) void vq_disc(
    const float* __restrict__ zq, const float* __restrict__ e,
    const unsigned short* __restrict__ ord, const int* __restrict__ Kc,
    float* __restrict__ disc)
{
  const int tid = threadIdx.x, bid = blockIdx.x;
  #pragma unroll
  for (int it = 0; it < 2; ++it) {
    int id  = bid * 512 + it * 256 + tid;
    int row = id >> 6;
    int c4  = (id & 63) << 2;
    int b   = row >> 11;
    int j   = row & (NT - 1);
    int K   = Kc[b];
    float4 v;
    if (j < K) {
      int src = ord[(b << 11) + j];
      v = *(const float4*)(zq + ((size_t)(b << 11) + src) * NC + c4);
    } else {
      v = *(const float4*)(e + c4);
    }
    *(float4*)(disc + (size_t)row * NC + c4) = v;
  }
}

// ---- losses ----
__global__ void vq_final(const float* __restrict__ hist, const float* __restrict__ cpart,
                         const float* __restrict__ mpart, float* __restrict__ out) {
  int t = threadIdx.x;
  double csum = 0, msum = 0, hsum = 0;
  #pragma unroll
  for (int i = 0; i < 4; ++i) {
    csum += (double)cpart[i * 256 + t];
    msum += (double)mpart[i * 256 + t];
  }
  double h[4];
  #pragma unroll
  for (int i = 0; i < 4; ++i) { h[i] = (double)hist[i * 256 + t]; hsum += h[i]; }
  #pragma unroll
  for (int off = 32; off; off >>= 1) {
    csum += __shfl_down(csum, off, 64);
    msum += __shfl_down(msum, off, 64);
    hsum += __shfl_down(hsum, off, 64);
  }
  __shared__ double wc[4], wm[4], wh[4];
  __shared__ double tots[3];
  if ((t & 63) == 0) { int w = t >> 6; wc[w] = csum; wm[w] = msum; wh[w] = hsum; }
  __syncthreads();
  if (t == 0) {
    tots[0] = wc[0] + wc[1] + wc[2] + wc[3];
    tots[1] = wm[0] + wm[1] + wm[2] + wm[3];
    tots[2] = wh[0] + wh[1] + wh[2] + wh[3];
  }
  __syncthreads();
  double tot = tots[2] + 1e-8;
  double dv = 0;
  #pragma unroll
  for (int i = 0; i < 4; ++i) {
    double p = h[i] / tot;
    dv += p * log(p * 1024.0 + 1e-8);
  }
  #pragma unroll
  for (int off = 32; off; off >>= 1) dv += __shfl_down(dv, off, 64);
  if ((t & 63) == 0) wc[t >> 6] = dv;
  __syncthreads();
  if (t == 0) {
    out[1] = (float)(wc[0] + wc[1] + wc[2] + wc[3]);
    out[0] = (float)(tots[0] / (tots[1] * 256.0));
  }
}

extern "C" void kernel_launch(void* const* d_in, const int* in_sizes, int n_in,
                              void* d_out, int out_size, void* d_ws, size_t ws_size,
                              hipStream_t stream) {
  if (ws_size < (size_t)WS_REQ) return;

  const float* z    = (const float*)d_in[0];
  const float* e    = (const float*)d_in[1];
  const float* mask = (const float*)d_in[2];
  float* out = (float*)d_out;
  char* ws = (char*)d_ws;

  float*          hist  = (float*)(ws + HIST_OFF);
  float*          en    = (float*)(ws + EN_OFF);
  float*          cpart = (float*)(ws + CPART_OFF);
  float*          mpart = (float*)(ws + MPART_OFF);
  unsigned short* ord   = (unsigned short*)(ws + ORD_OFF);
  int*            Kc    = (int*)(ws + KC_OFF);

  float* zq   = out + 2;
  float* disc = out + 2 + (size_t)BT * NC;
  float* idxf = out + 2 + (size_t)2 * BT * NC;

  // e-limb scratch lives at the start of the disc output region (1.5 MB of
  // 16.8 MB); consumed by vq_main_fused, overwritten later by vq_disc.
  short* e1 = (short*)disc;
  short* e2 = e1 + (size_t)NV * NC;
  short* e3 = e2 + (size_t)NV * NC;

  hipMemsetAsync(ws + HIST_OFF, 0, 4096, stream);
  vq_prep_e    <<<32, 256, 0, stream>>>(e, e1, e2, e3, en);
  vq_main_fused<<<256, 1024, 0, stream>>>(z, e1, e2, e3, en, mask, hist, idxf);
  vq_gather    <<<1024, 256, 0, stream>>>(z, e, mask, idxf, zq, cpart, mpart);
  vq_scan      <<<NB, 256, 0, stream>>>(idxf, ord, Kc);
  vq_disc      <<<2048, 256, 0, stream>>>(zq, e, ord, Kc, disc);
  vq_final     <<<1, NC, 0, stream>>>(hist, cpart, mpart, out);
}